// Round 3
// baseline (1064.977 us; speedup 1.0000x reference)
//
#include <hip/hip_runtime.h>

#define NB 4
#define NN 20000
#define NE 320000
#define ND 64
#define NR 64
#define NT 1000
#define NL 6
#define LN_EPS 1e-5f

// State layout: x is [N, B, D] (node-major). One node's data for all 4
// batches = 1 KB contiguous -> one dwordx4 per wave fetches it all.
// rel is [R, B, D] for the same reason.

// ---------------------------------------------------------------- utilities
__global__ void zero_f4(float4* __restrict__ p, int n4) {
    int i = blockIdx.x * blockDim.x + threadIdx.x;
    if (i < n4) p[i] = make_float4(0.f, 0.f, 0.f, 0.f);
}

__global__ void zero_i(int* __restrict__ p, int n) {
    int i = blockIdx.x * blockDim.x + threadIdx.x;
    if (i < n) p[i] = 0;
}

// query[b,d] = relrep[b, r_index[b], d]   (relrep stays [B,R,D] input layout)
__global__ void compute_query(const float* __restrict__ relrep,
                              const int* __restrict__ r_index,
                              float* __restrict__ query) {
    int tid = threadIdx.x;
    int b = tid >> 6, d = tid & 63;
    query[tid] = relrep[(b * NR + r_index[b]) * ND + d];
}

// buf[h_index[b], b, d] = query[b,d]  (buf pre-zeroed, [N,B,D])
__global__ void scatter_query(float* __restrict__ buf,
                              const float* __restrict__ query,
                              const int* __restrict__ h_index) {
    int tid = threadIdx.x;
    int b = tid >> 6;
    buf[(h_index[b] * NB + b) * ND + (tid & 63)] = query[tid];
}

// ---------------------------------------------------------------- CSR build
__global__ void hist_dst(const int* __restrict__ ei, int* __restrict__ deg) {
    int e = blockIdx.x * blockDim.x + threadIdx.x;
    if (e < NE) atomicAdd(&deg[ei[NE + e]], 1);
}

__global__ void scan_deg(const int* __restrict__ deg, int* __restrict__ row_off,
                         int* __restrict__ cursor) {
    __shared__ int tmp[1024];
    __shared__ int carry;
    if (threadIdx.x == 0) carry = 0;
    __syncthreads();
    for (int base = 0; base < NN; base += 1024) {
        int i = base + (int)threadIdx.x;
        int v = (i < NN) ? deg[i] : 0;
        tmp[threadIdx.x] = v;
        __syncthreads();
        for (int o = 1; o < 1024; o <<= 1) {
            int t = (threadIdx.x >= o) ? tmp[threadIdx.x - o] : 0;
            __syncthreads();
            tmp[threadIdx.x] += t;
            __syncthreads();
        }
        int excl = tmp[threadIdx.x] - v;
        if (i < NN) { row_off[i] = carry + excl; cursor[i] = carry + excl; }
        __syncthreads();
        if (threadIdx.x == 0) carry += tmp[1023];
        __syncthreads();
    }
    if (threadIdx.x == 0) row_off[NN] = carry;
}

// pack (src, type, weight) into one int4 per edge, CSR-sorted by dst
__global__ void scatter_edges(const int* __restrict__ ei, const int* __restrict__ et,
                              const float* __restrict__ ew, int* __restrict__ cursor,
                              int4* __restrict__ epack) {
    int e = blockIdx.x * blockDim.x + threadIdx.x;
    if (e >= NE) return;
    int d = ei[NE + e];
    int p = atomicAdd(&cursor[d], 1);
    epack[p] = make_int4(ei[e], et[e], __float_as_int(ew[e]), 0);
}

// rel[r,b,:] = relu(relrep[b,r,:] @ w1 + b1) @ w2 + b2 ; one wave per (b,r)
__global__ void rel_mlp(const float* __restrict__ relrep,
                        const float* __restrict__ w1, const float* __restrict__ b1,
                        const float* __restrict__ w2, const float* __restrict__ b2,
                        float* __restrict__ rel) {
    __shared__ float sin[ND];
    __shared__ float shid[ND];
    int br = blockIdx.x;                 // b*NR + r
    int b = br >> 6, r = br & 63;
    int j = threadIdx.x;
    sin[j] = relrep[br * ND + j];
    __syncthreads();
    float acc = b1[j];
    #pragma unroll 8
    for (int k = 0; k < ND; ++k) acc += sin[k] * w1[k * ND + j];
    shid[j] = fmaxf(acc, 0.f);
    __syncthreads();
    float out = b2[j];
    #pragma unroll 8
    for (int k = 0; k < ND; ++k) out += shid[k] * w2[k * ND + j];
    rel[(r * NB + b) * ND + j] = out;    // [R,B,D]
}

// ------------------------------------------------ fused gather+conv+LN layer
// one wave per node; gather lane layout: b = lane>>4, channels 4*(lane&15)+0..3
__global__ void __launch_bounds__(256)
fused_layer(const float* __restrict__ x, const float* __restrict__ rel,
            const int* __restrict__ row_off, const int4* __restrict__ epack,
            const float* __restrict__ query, const int* __restrict__ h_index,
            const float* __restrict__ cw, const float* __restrict__ cb,
            const float* __restrict__ g, const float* __restrict__ bb,
            float* __restrict__ xo) {
    __shared__ float sagg[4][NB * ND];
    int n = blockIdx.x * 4 + (threadIdx.x >> 6);
    int wv = threadIdx.x >> 6;
    int lane = threadIdx.x & 63;
    int beg = row_off[n], end = row_off[n + 1];

    const float4* __restrict__ xf4 = (const float4*)x;
    const float4* __restrict__ rf4 = (const float4*)rel;

    float4 agg4 = make_float4(0.f, 0.f, 0.f, 0.f);
    for (int e0 = beg; e0 < end; e0 += 64) {
        int cnt = min(64, end - e0);
        int4 ed = make_int4(0, 0, 0, 0);
        if (lane < cnt) ed = epack[e0 + lane];
        for (int j = 0; j < cnt; ++j) {
            int s   = __shfl(ed.x, j);
            int t   = __shfl(ed.y, j);
            float w = __int_as_float(__shfl(ed.z, j));
            float4 xv4 = xf4[s * 64 + lane];   // 1 KB: all batches of x[s]
            float4 rv4 = rf4[t * 64 + lane];
            agg4.x = fmaf(xv4.x * rv4.x, w, agg4.x);
            agg4.y = fmaf(xv4.y * rv4.y, w, agg4.y);
            agg4.z = fmaf(xv4.z * rv4.z, w, agg4.z);
            agg4.w = fmaf(xv4.w * rv4.w, w, agg4.w);
        }
    }
    // boundary self-loop: batch b = lane>>4
    {
        int b = lane >> 4;
        if (n == h_index[b]) {
            const float4* qf4 = (const float4*)query;
            float4 q4 = qf4[lane];             // query[b, 4*(lane&15)..]
            agg4.x += q4.x; agg4.y += q4.y; agg4.z += q4.z; agg4.w += q4.w;
        }
    }
    // transpose agg to lane=channel layout via LDS (1 KB per wave)
    ((float4*)sagg[wv])[lane] = agg4;
    __syncthreads();
    float aggs[NB], xv[NB], accs[NB];
    #pragma unroll
    for (int b = 0; b < NB; ++b) {
        aggs[b] = sagg[wv][b * ND + lane];
        xv[b]   = x[(n * NB + b) * ND + lane];
        accs[b] = cb[lane];
    }
    // conv: concat(x, agg) @ cw + cb
    for (int k = 0; k < ND; ++k) {
        float wk = cw[k * ND + lane];
        #pragma unroll
        for (int b = 0; b < NB; ++b) accs[b] += __shfl(xv[b], k) * wk;
    }
    for (int k = 0; k < ND; ++k) {
        float wk = cw[(ND + k) * ND + lane];
        #pragma unroll
        for (int b = 0; b < NB; ++b) accs[b] += __shfl(aggs[b], k) * wk;
    }
    // LN + relu + residual
    float gl = g[lane], bl = bb[lane];
    #pragma unroll
    for (int b = 0; b < NB; ++b) {
        float acc = accs[b];
        float s = acc, s2 = acc * acc;
        #pragma unroll
        for (int o = 32; o > 0; o >>= 1) { s += __shfl_xor(s, o); s2 += __shfl_xor(s2, o); }
        float mu  = s * (1.f / ND);
        float var = s2 * (1.f / ND) - mu * mu;
        float hn  = (acc - mu) * rsqrtf(var + LN_EPS) * gl + bl;
        xo[(n * NB + b) * ND + lane] = fmaxf(hn, 0.f) + xv[b];
    }
}

// score[b,t] = relu(concat(x[ti,b,:],query[b,:]) @ W1 + b1) @ W2 + b2
__global__ void final_score(const float* __restrict__ x, const float* __restrict__ query,
                            const int* __restrict__ t_index,
                            const float* __restrict__ w1, const float* __restrict__ b1,
                            const float* __restrict__ w2, const float* __restrict__ b2,
                            float* __restrict__ out) {
    int gid = blockIdx.x * 4 + (threadIdx.x >> 6);
    int lane = threadIdx.x & 63;
    int b = gid / NT;
    int ti = t_index[gid];
    float xv = x[(ti * NB + b) * ND + lane];
    float qv = query[b * ND + lane];
    float a0 = b1[lane], a1 = b1[lane + 64];
    #pragma unroll 8
    for (int k = 0; k < ND; ++k) {
        float f = __shfl(xv, k);
        a0 += f * w1[k * 128 + lane];
        a1 += f * w1[k * 128 + lane + 64];
    }
    #pragma unroll 8
    for (int k = 0; k < ND; ++k) {
        float f = __shfl(qv, k);
        a0 += f * w1[(ND + k) * 128 + lane];
        a1 += f * w1[(ND + k) * 128 + lane + 64];
    }
    a0 = fmaxf(a0, 0.f);
    a1 = fmaxf(a1, 0.f);
    float p = a0 * w2[lane] + a1 * w2[lane + 64];
    #pragma unroll
    for (int o = 32; o > 0; o >>= 1) p += __shfl_xor(p, o);
    if (lane == 0) out[gid] = p + b2[0];
}

extern "C" void kernel_launch(void* const* d_in, const int* in_sizes, int n_in,
                              void* d_out, int out_size, void* d_ws, size_t ws_size,
                              hipStream_t stream) {
    const int*   edge_index  = (const int*)d_in[0];
    const int*   edge_type   = (const int*)d_in[1];
    const float* relrep      = (const float*)d_in[2];
    const int*   h_index     = (const int*)d_in[3];
    const int*   r_index     = (const int*)d_in[4];
    const int*   t_index     = (const int*)d_in[5];
    const float* edge_weight = (const float*)d_in[6];
    const float* rp_w1  = (const float*)d_in[7];
    const float* rp_b1  = (const float*)d_in[8];
    const float* rp_w2  = (const float*)d_in[9];
    const float* rp_b2  = (const float*)d_in[10];
    const float* conv_w = (const float*)d_in[11];
    const float* conv_b = (const float*)d_in[12];
    const float* ln_g   = (const float*)d_in[13];
    const float* ln_b   = (const float*)d_in[14];
    const float* mlp_w1 = (const float*)d_in[15];
    const float* mlp_b1 = (const float*)d_in[16];
    const float* mlp_w2 = (const float*)d_in[17];
    const float* mlp_b2 = (const float*)d_in[18];
    float* out = (float*)d_out;

    const int BND = NB * NN * ND;            // 5,120,000 floats
    float* ws    = (float*)d_ws;
    float* query = ws;                       // 256
    float* rel   = query + 256;              // 16384  [R,B,D]
    float* x0    = rel + NB * NR * ND;       // BND    [N,B,D]
    float* x1    = x0 + BND;                 // BND
    int4*  epack = (int4*)(x1 + BND);        // NE int4
    int*   deg   = (int*)(epack + NE);       // NN
    int*   row_off = deg + NN;               // NN+1
    int*   cursor  = row_off + NN + 1;       // NN
    // total ≈ 46.5 MB

    // --- CSR build (once per call, reused across 6 layers) ---
    zero_i<<<(NN + 255) / 256, 256, 0, stream>>>(deg, NN);
    hist_dst<<<(NE + 255) / 256, 256, 0, stream>>>(edge_index, deg);
    scan_deg<<<1, 1024, 0, stream>>>(deg, row_off, cursor);
    scatter_edges<<<(NE + 255) / 256, 256, 0, stream>>>(edge_index, edge_type, edge_weight,
                                                        cursor, epack);

    // --- boundary / x0 ---
    compute_query<<<1, 256, 0, stream>>>(relrep, r_index, query);
    zero_f4<<<BND / 4 / 256, 256, 0, stream>>>((float4*)x0, BND / 4);
    scatter_query<<<1, 256, 0, stream>>>(x0, query, h_index);

    float* xc = x0;
    float* xn = x1;
    for (int l = 0; l < NL; ++l) {
        rel_mlp<<<NB * NR, 64, 0, stream>>>(relrep,
                                            rp_w1 + l * ND * ND, rp_b1 + l * ND,
                                            rp_w2 + l * ND * ND, rp_b2 + l * ND, rel);
        fused_layer<<<NN / 4, 256, 0, stream>>>(xc, rel, row_off, epack,
                                                query, h_index,
                                                conv_w + l * 2 * ND * ND, conv_b + l * ND,
                                                ln_g + l * ND, ln_b + l * ND, xn);
        float* tmp = xc; xc = xn; xn = tmp;
    }
    final_score<<<NB * NT / 4, 256, 0, stream>>>(xc, query, t_index,
                                                 mlp_w1, mlp_b1, mlp_w2, mlp_b2, out);
}

// Round 4
// 1026.305 us; speedup vs baseline: 1.0377x; 1.0377x over previous
//
#include <hip/hip_runtime.h>

#define NB 4
#define NN 20000
#define NE 320000
#define ND 64
#define NR 64
#define NT 1000
#define NL 6
#define LN_EPS 1e-5f

// State layout: x is [N, B, D] (node-major). One node's data for all 4
// batches = 1 KB contiguous -> one dwordx4 per wave fetches it all.
// rel is [R, B, D] for the same reason.

// ---------------------------------------------------------------- utilities
__global__ void zero_f4(float4* __restrict__ p, int n4) {
    int i = blockIdx.x * blockDim.x + threadIdx.x;
    if (i < n4) p[i] = make_float4(0.f, 0.f, 0.f, 0.f);
}

__global__ void zero_i(int* __restrict__ p, int n) {
    int i = blockIdx.x * blockDim.x + threadIdx.x;
    if (i < n) p[i] = 0;
}

// query[b,d] = relrep[b, r_index[b], d]
__global__ void compute_query(const float* __restrict__ relrep,
                              const int* __restrict__ r_index,
                              float* __restrict__ query) {
    int tid = threadIdx.x;
    int b = tid >> 6, d = tid & 63;
    query[tid] = relrep[(b * NR + r_index[b]) * ND + d];
}

// buf[h_index[b], b, d] = query[b,d]  (buf pre-zeroed, [N,B,D])
__global__ void scatter_query(float* __restrict__ buf,
                              const float* __restrict__ query,
                              const int* __restrict__ h_index) {
    int tid = threadIdx.x;
    int b = tid >> 6;
    buf[(h_index[b] * NB + b) * ND + (tid & 63)] = query[tid];
}

// ---------------------------------------------------------------- CSR build
__global__ void hist_dst(const int* __restrict__ ei, int* __restrict__ deg) {
    int e = blockIdx.x * blockDim.x + threadIdx.x;
    if (e < NE) atomicAdd(&deg[ei[NE + e]], 1);
}

__global__ void scan_deg(const int* __restrict__ deg, int* __restrict__ row_off,
                         int* __restrict__ cursor) {
    __shared__ int tmp[1024];
    __shared__ int carry;
    if (threadIdx.x == 0) carry = 0;
    __syncthreads();
    for (int base = 0; base < NN; base += 1024) {
        int i = base + (int)threadIdx.x;
        int v = (i < NN) ? deg[i] : 0;
        tmp[threadIdx.x] = v;
        __syncthreads();
        for (int o = 1; o < 1024; o <<= 1) {
            int t = (threadIdx.x >= o) ? tmp[threadIdx.x - o] : 0;
            __syncthreads();
            tmp[threadIdx.x] += t;
            __syncthreads();
        }
        int excl = tmp[threadIdx.x] - v;
        if (i < NN) { row_off[i] = carry + excl; cursor[i] = carry + excl; }
        __syncthreads();
        if (threadIdx.x == 0) carry += tmp[1023];
        __syncthreads();
    }
    if (threadIdx.x == 0) row_off[NN] = carry;
}

// pack (src, type, weight) into one int4 per edge, CSR-sorted by dst
__global__ void scatter_edges(const int* __restrict__ ei, const int* __restrict__ et,
                              const float* __restrict__ ew, int* __restrict__ cursor,
                              int4* __restrict__ epack) {
    int e = blockIdx.x * blockDim.x + threadIdx.x;
    if (e >= NE) return;
    int d = ei[NE + e];
    int p = atomicAdd(&cursor[d], 1);
    epack[p] = make_int4(ei[e], et[e], __float_as_int(ew[e]), 0);
}

// rel[r,b,:] = relu(relrep[b,r,:] @ w1 + b1) @ w2 + b2 ; one wave per (b,r)
__global__ void rel_mlp(const float* __restrict__ relrep,
                        const float* __restrict__ w1, const float* __restrict__ b1,
                        const float* __restrict__ w2, const float* __restrict__ b2,
                        float* __restrict__ rel) {
    __shared__ float sin[ND];
    __shared__ float shid[ND];
    int br = blockIdx.x;                 // b*NR + r
    int b = br >> 6, r = br & 63;
    int j = threadIdx.x;
    sin[j] = relrep[br * ND + j];
    __syncthreads();
    float acc = b1[j];
    #pragma unroll 8
    for (int k = 0; k < ND; ++k) acc += sin[k] * w1[k * ND + j];
    shid[j] = fmaxf(acc, 0.f);
    __syncthreads();
    float out = b2[j];
    #pragma unroll 8
    for (int k = 0; k < ND; ++k) out += shid[k] * w2[k * ND + j];
    rel[(r * NB + b) * ND + j] = out;    // [R,B,D]
}

// ------------------------------------------------ fused gather+conv+LN layer
// one wave per node; gather lane layout: b = lane>>4, channels 4*(lane&15)+0..3
// Edge loop manually unrolled x4: 8 independent 1 KB loads in flight per wave.
__global__ void __launch_bounds__(256)
fused_layer(const float* __restrict__ x, const float* __restrict__ rel,
            const int* __restrict__ row_off, const int4* __restrict__ epack,
            const float* __restrict__ query, const int* __restrict__ h_index,
            const float* __restrict__ cw, const float* __restrict__ cb,
            const float* __restrict__ g, const float* __restrict__ bb,
            float* __restrict__ xo) {
    __shared__ float sagg[4][NB * ND];
    int n = blockIdx.x * 4 + (threadIdx.x >> 6);
    int wv = threadIdx.x >> 6;
    int lane = threadIdx.x & 63;
    int beg = row_off[n], end = row_off[n + 1];

    const float4* __restrict__ xf4 = (const float4*)x;
    const float4* __restrict__ rf4 = (const float4*)rel;

    float4 agg4 = make_float4(0.f, 0.f, 0.f, 0.f);
    for (int e0 = beg; e0 < end; e0 += 64) {
        int cnt = min(64, end - e0);
        int4 ed = make_int4(0, 0, 0, 0);
        if (lane < cnt) ed = epack[e0 + lane];
        int j = 0;
        for (; j + 4 <= cnt; j += 4) {
            int s0 = __shfl(ed.x, j    ), t0 = __shfl(ed.y, j    );
            int s1 = __shfl(ed.x, j + 1), t1 = __shfl(ed.y, j + 1);
            int s2 = __shfl(ed.x, j + 2), t2 = __shfl(ed.y, j + 2);
            int s3 = __shfl(ed.x, j + 3), t3 = __shfl(ed.y, j + 3);
            float w0 = __int_as_float(__shfl(ed.z, j    ));
            float w1 = __int_as_float(__shfl(ed.z, j + 1));
            float w2 = __int_as_float(__shfl(ed.z, j + 2));
            float w3 = __int_as_float(__shfl(ed.z, j + 3));
            float4 xa = xf4[s0 * 64 + lane], ra = rf4[t0 * 64 + lane];
            float4 xb = xf4[s1 * 64 + lane], rb = rf4[t1 * 64 + lane];
            float4 xc = xf4[s2 * 64 + lane], rc = rf4[t2 * 64 + lane];
            float4 xd = xf4[s3 * 64 + lane], rd = rf4[t3 * 64 + lane];
            agg4.x = fmaf(xa.x * ra.x, w0, agg4.x);
            agg4.y = fmaf(xa.y * ra.y, w0, agg4.y);
            agg4.z = fmaf(xa.z * ra.z, w0, agg4.z);
            agg4.w = fmaf(xa.w * ra.w, w0, agg4.w);
            agg4.x = fmaf(xb.x * rb.x, w1, agg4.x);
            agg4.y = fmaf(xb.y * rb.y, w1, agg4.y);
            agg4.z = fmaf(xb.z * rb.z, w1, agg4.z);
            agg4.w = fmaf(xb.w * rb.w, w1, agg4.w);
            agg4.x = fmaf(xc.x * rc.x, w2, agg4.x);
            agg4.y = fmaf(xc.y * rc.y, w2, agg4.y);
            agg4.z = fmaf(xc.z * rc.z, w2, agg4.z);
            agg4.w = fmaf(xc.w * rc.w, w2, agg4.w);
            agg4.x = fmaf(xd.x * rd.x, w3, agg4.x);
            agg4.y = fmaf(xd.y * rd.y, w3, agg4.y);
            agg4.z = fmaf(xd.z * rd.z, w3, agg4.z);
            agg4.w = fmaf(xd.w * rd.w, w3, agg4.w);
        }
        for (; j < cnt; ++j) {
            int s   = __shfl(ed.x, j);
            int t   = __shfl(ed.y, j);
            float w = __int_as_float(__shfl(ed.z, j));
            float4 xv4 = xf4[s * 64 + lane];
            float4 rv4 = rf4[t * 64 + lane];
            agg4.x = fmaf(xv4.x * rv4.x, w, agg4.x);
            agg4.y = fmaf(xv4.y * rv4.y, w, agg4.y);
            agg4.z = fmaf(xv4.z * rv4.z, w, agg4.z);
            agg4.w = fmaf(xv4.w * rv4.w, w, agg4.w);
        }
    }
    // boundary self-loop: batch b = lane>>4
    {
        int b = lane >> 4;
        if (n == h_index[b]) {
            const float4* qf4 = (const float4*)query;
            float4 q4 = qf4[lane];
            agg4.x += q4.x; agg4.y += q4.y; agg4.z += q4.z; agg4.w += q4.w;
        }
    }
    // transpose agg to lane=channel layout via LDS (1 KB per wave)
    ((float4*)sagg[wv])[lane] = agg4;
    __syncthreads();
    float aggs[NB], xv[NB], accs[NB];
    #pragma unroll
    for (int b = 0; b < NB; ++b) {
        aggs[b] = sagg[wv][b * ND + lane];
        xv[b]   = x[(n * NB + b) * ND + lane];
        accs[b] = cb[lane];
    }
    // conv: concat(x, agg) @ cw + cb
    for (int k = 0; k < ND; ++k) {
        float wk = cw[k * ND + lane];
        #pragma unroll
        for (int b = 0; b < NB; ++b) accs[b] += __shfl(xv[b], k) * wk;
    }
    for (int k = 0; k < ND; ++k) {
        float wk = cw[(ND + k) * ND + lane];
        #pragma unroll
        for (int b = 0; b < NB; ++b) accs[b] += __shfl(aggs[b], k) * wk;
    }
    // LN + relu + residual
    float gl = g[lane], bl = bb[lane];
    #pragma unroll
    for (int b = 0; b < NB; ++b) {
        float acc = accs[b];
        float s = acc, s2 = acc * acc;
        #pragma unroll
        for (int o = 32; o > 0; o >>= 1) { s += __shfl_xor(s, o); s2 += __shfl_xor(s2, o); }
        float mu  = s * (1.f / ND);
        float var = s2 * (1.f / ND) - mu * mu;
        float hn  = (acc - mu) * rsqrtf(var + LN_EPS) * gl + bl;
        xo[(n * NB + b) * ND + lane] = fmaxf(hn, 0.f) + xv[b];
    }
}

// score[b,t] = relu(concat(x[ti,b,:],query[b,:]) @ W1 + b1) @ W2 + b2
__global__ void final_score(const float* __restrict__ x, const float* __restrict__ query,
                            const int* __restrict__ t_index,
                            const float* __restrict__ w1, const float* __restrict__ b1,
                            const float* __restrict__ w2, const float* __restrict__ b2,
                            float* __restrict__ out) {
    int gid = blockIdx.x * 4 + (threadIdx.x >> 6);
    int lane = threadIdx.x & 63;
    int b = gid / NT;
    int ti = t_index[gid];
    float xv = x[(ti * NB + b) * ND + lane];
    float qv = query[b * ND + lane];
    float a0 = b1[lane], a1 = b1[lane + 64];
    #pragma unroll 8
    for (int k = 0; k < ND; ++k) {
        float f = __shfl(xv, k);
        a0 += f * w1[k * 128 + lane];
        a1 += f * w1[k * 128 + lane + 64];
    }
    #pragma unroll 8
    for (int k = 0; k < ND; ++k) {
        float f = __shfl(qv, k);
        a0 += f * w1[(ND + k) * 128 + lane];
        a1 += f * w1[(ND + k) * 128 + lane + 64];
    }
    a0 = fmaxf(a0, 0.f);
    a1 = fmaxf(a1, 0.f);
    float p = a0 * w2[lane] + a1 * w2[lane + 64];
    #pragma unroll
    for (int o = 32; o > 0; o >>= 1) p += __shfl_xor(p, o);
    if (lane == 0) out[gid] = p + b2[0];
}

extern "C" void kernel_launch(void* const* d_in, const int* in_sizes, int n_in,
                              void* d_out, int out_size, void* d_ws, size_t ws_size,
                              hipStream_t stream) {
    const int*   edge_index  = (const int*)d_in[0];
    const int*   edge_type   = (const int*)d_in[1];
    const float* relrep      = (const float*)d_in[2];
    const int*   h_index     = (const int*)d_in[3];
    const int*   r_index     = (const int*)d_in[4];
    const int*   t_index     = (const int*)d_in[5];
    const float* edge_weight = (const float*)d_in[6];
    const float* rp_w1  = (const float*)d_in[7];
    const float* rp_b1  = (const float*)d_in[8];
    const float* rp_w2  = (const float*)d_in[9];
    const float* rp_b2  = (const float*)d_in[10];
    const float* conv_w = (const float*)d_in[11];
    const float* conv_b = (const float*)d_in[12];
    const float* ln_g   = (const float*)d_in[13];
    const float* ln_b   = (const float*)d_in[14];
    const float* mlp_w1 = (const float*)d_in[15];
    const float* mlp_b1 = (const float*)d_in[16];
    const float* mlp_w2 = (const float*)d_in[17];
    const float* mlp_b2 = (const float*)d_in[18];
    float* out = (float*)d_out;

    const int BND = NB * NN * ND;            // 5,120,000 floats
    float* ws    = (float*)d_ws;
    float* query = ws;                       // 256
    float* rel   = query + 256;              // 16384  [R,B,D]
    float* x0    = rel + NB * NR * ND;       // BND    [N,B,D]
    float* x1    = x0 + BND;                 // BND
    int4*  epack = (int4*)(x1 + BND);        // NE int4
    int*   deg   = (int*)(epack + NE);       // NN
    int*   row_off = deg + NN;               // NN+1
    int*   cursor  = row_off + NN + 1;       // NN

    // --- CSR build (once per call, reused across 6 layers) ---
    zero_i<<<(NN + 255) / 256, 256, 0, stream>>>(deg, NN);
    hist_dst<<<(NE + 255) / 256, 256, 0, stream>>>(edge_index, deg);
    scan_deg<<<1, 1024, 0, stream>>>(deg, row_off, cursor);
    scatter_edges<<<(NE + 255) / 256, 256, 0, stream>>>(edge_index, edge_type, edge_weight,
                                                        cursor, epack);

    // --- boundary / x0 ---
    compute_query<<<1, 256, 0, stream>>>(relrep, r_index, query);
    zero_f4<<<BND / 4 / 256, 256, 0, stream>>>((float4*)x0, BND / 4);
    scatter_query<<<1, 256, 0, stream>>>(x0, query, h_index);

    float* xc = x0;
    float* xn = x1;
    for (int l = 0; l < NL; ++l) {
        rel_mlp<<<NB * NR, 64, 0, stream>>>(relrep,
                                            rp_w1 + l * ND * ND, rp_b1 + l * ND,
                                            rp_w2 + l * ND * ND, rp_b2 + l * ND, rel);
        fused_layer<<<NN / 4, 256, 0, stream>>>(xc, rel, row_off, epack,
                                                query, h_index,
                                                conv_w + l * 2 * ND * ND, conv_b + l * ND,
                                                ln_g + l * ND, ln_b + l * ND, xn);
        float* tmp = xc; xc = xn; xn = tmp;
    }
    final_score<<<NB * NT / 4, 256, 0, stream>>>(xc, query, t_index,
                                                 mlp_w1, mlp_b1, mlp_w2, mlp_b2, out);
}

// Round 5
// 1008.655 us; speedup vs baseline: 1.0558x; 1.0175x over previous
//
#include <hip/hip_runtime.h>
#include <hip/hip_fp16.h>

#define NB 4
#define NN 20000
#define NE 320000
#define ND 64
#define NR 64
#define NT 1000
#define NL 6
#define LN_EPS 1e-5f

// State: x fp32 [N,B,D] (exact path: conv/LN/residual/final) + fp16 mirror
// x16 [N,B,D] used ONLY for the edge gather (halves L2-miss bytes — the
// measured wall is ~1.05 TB/s on the L2-miss path, r2-r4 all pinned there).
// rel is fp16 [R,B,D] (gather-only consumer).

// ---------------------------------------------------------------- utilities
__global__ void zero_f4(float4* __restrict__ p, int n4) {
    int i = blockIdx.x * blockDim.x + threadIdx.x;
    if (i < n4) p[i] = make_float4(0.f, 0.f, 0.f, 0.f);
}

__global__ void zero_i(int* __restrict__ p, int n) {
    int i = blockIdx.x * blockDim.x + threadIdx.x;
    if (i < n) p[i] = 0;
}

__global__ void compute_query(const float* __restrict__ relrep,
                              const int* __restrict__ r_index,
                              float* __restrict__ query) {
    int tid = threadIdx.x;
    int b = tid >> 6, d = tid & 63;
    query[tid] = relrep[(b * NR + r_index[b]) * ND + d];
}

// seed x0 (fp32) and x16_0 (fp16) with query at h_index[b]
__global__ void scatter_query(float* __restrict__ buf, __half* __restrict__ buf16,
                              const float* __restrict__ query,
                              const int* __restrict__ h_index) {
    int tid = threadIdx.x;
    int b = tid >> 6, d = tid & 63;
    float q = query[tid];
    int off = (h_index[b] * NB + b) * ND + d;
    buf[off] = q;
    buf16[off] = __float2half(q);
}

// ---------------------------------------------------------------- CSR build
__global__ void hist_dst(const int* __restrict__ ei, int* __restrict__ deg) {
    int e = blockIdx.x * blockDim.x + threadIdx.x;
    if (e < NE) atomicAdd(&deg[ei[NE + e]], 1);
}

__global__ void scan_deg(const int* __restrict__ deg, int* __restrict__ row_off,
                         int* __restrict__ cursor) {
    __shared__ int tmp[1024];
    __shared__ int carry;
    if (threadIdx.x == 0) carry = 0;
    __syncthreads();
    for (int base = 0; base < NN; base += 1024) {
        int i = base + (int)threadIdx.x;
        int v = (i < NN) ? deg[i] : 0;
        tmp[threadIdx.x] = v;
        __syncthreads();
        for (int o = 1; o < 1024; o <<= 1) {
            int t = (threadIdx.x >= o) ? tmp[threadIdx.x - o] : 0;
            __syncthreads();
            tmp[threadIdx.x] += t;
            __syncthreads();
        }
        int excl = tmp[threadIdx.x] - v;
        if (i < NN) { row_off[i] = carry + excl; cursor[i] = carry + excl; }
        __syncthreads();
        if (threadIdx.x == 0) carry += tmp[1023];
        __syncthreads();
    }
    if (threadIdx.x == 0) row_off[NN] = carry;
}

__global__ void scatter_edges(const int* __restrict__ ei, const int* __restrict__ et,
                              const float* __restrict__ ew, int* __restrict__ cursor,
                              int4* __restrict__ epack) {
    int e = blockIdx.x * blockDim.x + threadIdx.x;
    if (e >= NE) return;
    int d = ei[NE + e];
    int p = atomicAdd(&cursor[d], 1);
    epack[p] = make_int4(ei[e], et[e], __float_as_int(ew[e]), 0);
}

// rel16[r,b,:] = fp16( relu(relrep[b,r,:] @ w1 + b1) @ w2 + b2 )
__global__ void rel_mlp(const float* __restrict__ relrep,
                        const float* __restrict__ w1, const float* __restrict__ b1,
                        const float* __restrict__ w2, const float* __restrict__ b2,
                        __half* __restrict__ rel16) {
    __shared__ float sin[ND];
    __shared__ float shid[ND];
    int br = blockIdx.x;                 // b*NR + r
    int b = br >> 6, r = br & 63;
    int j = threadIdx.x;
    sin[j] = relrep[br * ND + j];
    __syncthreads();
    float acc = b1[j];
    #pragma unroll 8
    for (int k = 0; k < ND; ++k) acc += sin[k] * w1[k * ND + j];
    shid[j] = fmaxf(acc, 0.f);
    __syncthreads();
    float out = b2[j];
    #pragma unroll 8
    for (int k = 0; k < ND; ++k) out += shid[k] * w2[k * ND + j];
    rel16[(r * NB + b) * ND + j] = __float2half(out);
}

__device__ __forceinline__ float2 h2f(unsigned u) {
    __half2 h = *(__half2*)&u;
    return __half22float2(h);
}

// ------------------------------------------------ fused gather+conv+LN layer
// one wave per node; gather lane layout: b = lane>>4, channels 4*(lane&15)+0..3
__global__ void __launch_bounds__(256)
fused_layer(const float* __restrict__ x, const __half* __restrict__ x16,
            const __half* __restrict__ rel16,
            const int* __restrict__ row_off, const int4* __restrict__ epack,
            const float* __restrict__ query, const int* __restrict__ h_index,
            const float* __restrict__ cw, const float* __restrict__ cb,
            const float* __restrict__ g, const float* __restrict__ bb,
            float* __restrict__ xo, __half* __restrict__ xo16) {
    __shared__ float sagg[4][NB * ND];
    int n = blockIdx.x * 4 + (threadIdx.x >> 6);
    int wv = threadIdx.x >> 6;
    int lane = threadIdx.x & 63;
    int beg = row_off[n], end = row_off[n + 1];

    const uint2* __restrict__ x2 = (const uint2*)x16;    // 4 halves / lane
    const uint2* __restrict__ r2 = (const uint2*)rel16;

    float4 agg4 = make_float4(0.f, 0.f, 0.f, 0.f);
    for (int e0 = beg; e0 < end; e0 += 64) {
        int cnt = min(64, end - e0);
        int4 ed = make_int4(0, 0, 0, 0);
        if (lane < cnt) ed = epack[e0 + lane];
        int j = 0;
        for (; j + 4 <= cnt; j += 4) {
            int s0 = __shfl(ed.x, j    ), t0 = __shfl(ed.y, j    );
            int s1 = __shfl(ed.x, j + 1), t1 = __shfl(ed.y, j + 1);
            int s2 = __shfl(ed.x, j + 2), t2 = __shfl(ed.y, j + 2);
            int s3 = __shfl(ed.x, j + 3), t3 = __shfl(ed.y, j + 3);
            float w0 = __int_as_float(__shfl(ed.z, j    ));
            float w1 = __int_as_float(__shfl(ed.z, j + 1));
            float w2 = __int_as_float(__shfl(ed.z, j + 2));
            float w3 = __int_as_float(__shfl(ed.z, j + 3));
            uint2 xa = x2[s0 * 64 + lane], ra = r2[t0 * 64 + lane];
            uint2 xb = x2[s1 * 64 + lane], rb = r2[t1 * 64 + lane];
            uint2 xc = x2[s2 * 64 + lane], rc = r2[t2 * 64 + lane];
            uint2 xd = x2[s3 * 64 + lane], rd = r2[t3 * 64 + lane];
            float2 p0, p1, q0, q1;
            p0 = h2f(xa.x); p1 = h2f(xa.y); q0 = h2f(ra.x); q1 = h2f(ra.y);
            agg4.x = fmaf(p0.x * q0.x, w0, agg4.x);
            agg4.y = fmaf(p0.y * q0.y, w0, agg4.y);
            agg4.z = fmaf(p1.x * q1.x, w0, agg4.z);
            agg4.w = fmaf(p1.y * q1.y, w0, agg4.w);
            p0 = h2f(xb.x); p1 = h2f(xb.y); q0 = h2f(rb.x); q1 = h2f(rb.y);
            agg4.x = fmaf(p0.x * q0.x, w1, agg4.x);
            agg4.y = fmaf(p0.y * q0.y, w1, agg4.y);
            agg4.z = fmaf(p1.x * q1.x, w1, agg4.z);
            agg4.w = fmaf(p1.y * q1.y, w1, agg4.w);
            p0 = h2f(xc.x); p1 = h2f(xc.y); q0 = h2f(rc.x); q1 = h2f(rc.y);
            agg4.x = fmaf(p0.x * q0.x, w2, agg4.x);
            agg4.y = fmaf(p0.y * q0.y, w2, agg4.y);
            agg4.z = fmaf(p1.x * q1.x, w2, agg4.z);
            agg4.w = fmaf(p1.y * q1.y, w2, agg4.w);
            p0 = h2f(xd.x); p1 = h2f(xd.y); q0 = h2f(rd.x); q1 = h2f(rd.y);
            agg4.x = fmaf(p0.x * q0.x, w3, agg4.x);
            agg4.y = fmaf(p0.y * q0.y, w3, agg4.y);
            agg4.z = fmaf(p1.x * q1.x, w3, agg4.z);
            agg4.w = fmaf(p1.y * q1.y, w3, agg4.w);
        }
        for (; j < cnt; ++j) {
            int s   = __shfl(ed.x, j);
            int t   = __shfl(ed.y, j);
            float w = __int_as_float(__shfl(ed.z, j));
            uint2 xa = x2[s * 64 + lane], ra = r2[t * 64 + lane];
            float2 p0 = h2f(xa.x), p1 = h2f(xa.y), q0 = h2f(ra.x), q1 = h2f(ra.y);
            agg4.x = fmaf(p0.x * q0.x, w, agg4.x);
            agg4.y = fmaf(p0.y * q0.y, w, agg4.y);
            agg4.z = fmaf(p1.x * q1.x, w, agg4.z);
            agg4.w = fmaf(p1.y * q1.y, w, agg4.w);
        }
    }
    // boundary self-loop: batch b = lane>>4, channels 4*(lane&15)..
    {
        int b = lane >> 4;
        if (n == h_index[b]) {
            const float4* qf4 = (const float4*)query;
            float4 q4 = qf4[lane];
            agg4.x += q4.x; agg4.y += q4.y; agg4.z += q4.z; agg4.w += q4.w;
        }
    }
    // transpose agg to lane=channel layout via LDS (1 KB per wave)
    ((float4*)sagg[wv])[lane] = agg4;
    __syncthreads();
    float aggs[NB], xv[NB], accs[NB];
    #pragma unroll
    for (int b = 0; b < NB; ++b) {
        aggs[b] = sagg[wv][b * ND + lane];
        xv[b]   = x[(n * NB + b) * ND + lane];
        accs[b] = cb[lane];
    }
    // conv: concat(x, agg) @ cw + cb
    for (int k = 0; k < ND; ++k) {
        float wk = cw[k * ND + lane];
        #pragma unroll
        for (int b = 0; b < NB; ++b) accs[b] += __shfl(xv[b], k) * wk;
    }
    for (int k = 0; k < ND; ++k) {
        float wk = cw[(ND + k) * ND + lane];
        #pragma unroll
        for (int b = 0; b < NB; ++b) accs[b] += __shfl(aggs[b], k) * wk;
    }
    // LN + relu + residual; write fp32 + fp16 mirror
    float gl = g[lane], bl = bb[lane];
    #pragma unroll
    for (int b = 0; b < NB; ++b) {
        float acc = accs[b];
        float s = acc, s2 = acc * acc;
        #pragma unroll
        for (int o = 32; o > 0; o >>= 1) { s += __shfl_xor(s, o); s2 += __shfl_xor(s2, o); }
        float mu  = s * (1.f / ND);
        float var = s2 * (1.f / ND) - mu * mu;
        float hn  = (acc - mu) * rsqrtf(var + LN_EPS) * gl + bl;
        float v   = fmaxf(hn, 0.f) + xv[b];
        xo[(n * NB + b) * ND + lane] = v;
        xo16[(n * NB + b) * ND + lane] = __float2half(v);
    }
}

// score[b,t] = relu(concat(x[ti,b,:],query[b,:]) @ W1 + b1) @ W2 + b2
__global__ void final_score(const float* __restrict__ x, const float* __restrict__ query,
                            const int* __restrict__ t_index,
                            const float* __restrict__ w1, const float* __restrict__ b1,
                            const float* __restrict__ w2, const float* __restrict__ b2,
                            float* __restrict__ out) {
    int gid = blockIdx.x * 4 + (threadIdx.x >> 6);
    int lane = threadIdx.x & 63;
    int b = gid / NT;
    int ti = t_index[gid];
    float xv = x[(ti * NB + b) * ND + lane];
    float qv = query[b * ND + lane];
    float a0 = b1[lane], a1 = b1[lane + 64];
    #pragma unroll 8
    for (int k = 0; k < ND; ++k) {
        float f = __shfl(xv, k);
        a0 += f * w1[k * 128 + lane];
        a1 += f * w1[k * 128 + lane + 64];
    }
    #pragma unroll 8
    for (int k = 0; k < ND; ++k) {
        float f = __shfl(qv, k);
        a0 += f * w1[(ND + k) * 128 + lane];
        a1 += f * w1[(ND + k) * 128 + lane + 64];
    }
    a0 = fmaxf(a0, 0.f);
    a1 = fmaxf(a1, 0.f);
    float p = a0 * w2[lane] + a1 * w2[lane + 64];
    #pragma unroll
    for (int o = 32; o > 0; o >>= 1) p += __shfl_xor(p, o);
    if (lane == 0) out[gid] = p + b2[0];
}

extern "C" void kernel_launch(void* const* d_in, const int* in_sizes, int n_in,
                              void* d_out, int out_size, void* d_ws, size_t ws_size,
                              hipStream_t stream) {
    const int*   edge_index  = (const int*)d_in[0];
    const int*   edge_type   = (const int*)d_in[1];
    const float* relrep      = (const float*)d_in[2];
    const int*   h_index     = (const int*)d_in[3];
    const int*   r_index     = (const int*)d_in[4];
    const int*   t_index     = (const int*)d_in[5];
    const float* edge_weight = (const float*)d_in[6];
    const float* rp_w1  = (const float*)d_in[7];
    const float* rp_b1  = (const float*)d_in[8];
    const float* rp_w2  = (const float*)d_in[9];
    const float* rp_b2  = (const float*)d_in[10];
    const float* conv_w = (const float*)d_in[11];
    const float* conv_b = (const float*)d_in[12];
    const float* ln_g   = (const float*)d_in[13];
    const float* ln_b   = (const float*)d_in[14];
    const float* mlp_w1 = (const float*)d_in[15];
    const float* mlp_b1 = (const float*)d_in[16];
    const float* mlp_w2 = (const float*)d_in[17];
    const float* mlp_b2 = (const float*)d_in[18];
    float* out = (float*)d_out;

    const int BND = NB * NN * ND;              // 5,120,000
    float*  ws     = (float*)d_ws;
    float*  query  = ws;                       // 256
    __half* rel16  = (__half*)(query + 256);   // 16384 halves
    float*  x0     = (float*)(rel16 + NB * NR * ND);  // BND fp32
    float*  x1     = x0 + BND;                 // BND fp32
    __half* x16a   = (__half*)(x1 + BND);      // BND halves
    __half* x16b   = x16a + BND;               // BND halves
    int4*   epack  = (int4*)(x16b + BND);      // NE int4
    int*    deg    = (int*)(epack + NE);       // NN
    int*    row_off = deg + NN;                // NN+1
    int*    cursor  = row_off + NN + 1;        // NN
    // total ≈ 67 MB

    // --- CSR build (once per call, reused across 6 layers) ---
    zero_i<<<(NN + 255) / 256, 256, 0, stream>>>(deg, NN);
    hist_dst<<<(NE + 255) / 256, 256, 0, stream>>>(edge_index, deg);
    scan_deg<<<1, 1024, 0, stream>>>(deg, row_off, cursor);
    scatter_edges<<<(NE + 255) / 256, 256, 0, stream>>>(edge_index, edge_type, edge_weight,
                                                        cursor, epack);

    // --- boundary / x0 (fp32 + fp16 mirror) ---
    compute_query<<<1, 256, 0, stream>>>(relrep, r_index, query);
    zero_f4<<<BND / 4 / 256, 256, 0, stream>>>((float4*)x0, BND / 4);
    zero_f4<<<BND / 8 / 256, 256, 0, stream>>>((float4*)x16a, BND / 8);
    scatter_query<<<1, 256, 0, stream>>>(x0, x16a, query, h_index);

    float*  xc = x0;   float*  xn = x1;
    __half* mc = x16a; __half* mn = x16b;
    for (int l = 0; l < NL; ++l) {
        rel_mlp<<<NB * NR, 64, 0, stream>>>(relrep,
                                            rp_w1 + l * ND * ND, rp_b1 + l * ND,
                                            rp_w2 + l * ND * ND, rp_b2 + l * ND, rel16);
        fused_layer<<<NN / 4, 256, 0, stream>>>(xc, mc, rel16, row_off, epack,
                                                query, h_index,
                                                conv_w + l * 2 * ND * ND, conv_b + l * ND,
                                                ln_g + l * ND, ln_b + l * ND, xn, mn);
        float* tf = xc; xc = xn; xn = tf;
        __half* th = mc; mc = mn; mn = th;
    }
    final_score<<<NB * NT / 4, 256, 0, stream>>>(xc, query, t_index,
                                                 mlp_w1, mlp_b1, mlp_w2, mlp_b2, out);
}

// Round 6
// 464.817 us; speedup vs baseline: 2.2912x; 2.1700x over previous
//
#include <hip/hip_runtime.h>
#include <hip/hip_fp16.h>

#define NB 4
#define NN 20000
#define NE 320000
#define ND 64
#define NR 64
#define NT 1000
#define NL 6
#define LN_EPS 1e-5f

typedef _Float16 half8 __attribute__((ext_vector_type(8)));
typedef _Float16 half4v __attribute__((ext_vector_type(4)));
typedef float floatx4 __attribute__((ext_vector_type(4)));

// State: x fp32 [N,B,D] (exact residual/final path) + fp16 mirror x16 [N,B,D]
// used for the edge gather AND as the conv's A-operand. rel fp16 [R,B,D].
// Conv is done with MFMA 16x16x32 f16 per block (16 rows = 4 nodes x 4
// batches, K=128, N=64) -- replaces the 512-bpermute shuffle conv that was
// the measured wall (~142us/layer invariant across r2-r5).

// ---------------------------------------------------------------- utilities
__global__ void zero_f4(float4* __restrict__ p, int n4) {
    int i = blockIdx.x * blockDim.x + threadIdx.x;
    if (i < n4) p[i] = make_float4(0.f, 0.f, 0.f, 0.f);
}

__global__ void zero_i(int* __restrict__ p, int n) {
    int i = blockIdx.x * blockDim.x + threadIdx.x;
    if (i < n) p[i] = 0;
}

__global__ void compute_query(const float* __restrict__ relrep,
                              const int* __restrict__ r_index,
                              float* __restrict__ query) {
    int tid = threadIdx.x;
    int b = tid >> 6, d = tid & 63;
    query[tid] = relrep[(b * NR + r_index[b]) * ND + d];
}

__global__ void scatter_query(float* __restrict__ buf, __half* __restrict__ buf16,
                              const float* __restrict__ query,
                              const int* __restrict__ h_index) {
    int tid = threadIdx.x;
    int b = tid >> 6, d = tid & 63;
    float q = query[tid];
    int off = (h_index[b] * NB + b) * ND + d;
    buf[off] = q;
    buf16[off] = __float2half(q);
}

// conv_w [L][2D][D] fp32 -> transposed fp16 [L][D out][2D in]
__global__ void conv_w_prep(const float* __restrict__ cw, _Float16* __restrict__ cwt) {
    int i = blockIdx.x * 256 + threadIdx.x;          // over L*128*64
    if (i >= NL * 128 * 64) return;
    int l = i >> 13, rem = i & 8191, k = rem >> 6, n = rem & 63;
    cwt[l * 8192 + n * 128 + k] = (_Float16)cw[i];
}

// ---------------------------------------------------------------- CSR build
__global__ void hist_dst(const int* __restrict__ ei, int* __restrict__ deg) {
    int e = blockIdx.x * blockDim.x + threadIdx.x;
    if (e < NE) atomicAdd(&deg[ei[NE + e]], 1);
}

__global__ void scan_deg(const int* __restrict__ deg, int* __restrict__ row_off,
                         int* __restrict__ cursor) {
    __shared__ int tmp[1024];
    __shared__ int carry;
    if (threadIdx.x == 0) carry = 0;
    __syncthreads();
    for (int base = 0; base < NN; base += 1024) {
        int i = base + (int)threadIdx.x;
        int v = (i < NN) ? deg[i] : 0;
        tmp[threadIdx.x] = v;
        __syncthreads();
        for (int o = 1; o < 1024; o <<= 1) {
            int t = (threadIdx.x >= o) ? tmp[threadIdx.x - o] : 0;
            __syncthreads();
            tmp[threadIdx.x] += t;
            __syncthreads();
        }
        int excl = tmp[threadIdx.x] - v;
        if (i < NN) { row_off[i] = carry + excl; cursor[i] = carry + excl; }
        __syncthreads();
        if (threadIdx.x == 0) carry += tmp[1023];
        __syncthreads();
    }
    if (threadIdx.x == 0) row_off[NN] = carry;
}

__global__ void scatter_edges(const int* __restrict__ ei, const int* __restrict__ et,
                              const float* __restrict__ ew, int* __restrict__ cursor,
                              int4* __restrict__ epack) {
    int e = blockIdx.x * blockDim.x + threadIdx.x;
    if (e >= NE) return;
    int d = ei[NE + e];
    int p = atomicAdd(&cursor[d], 1);
    epack[p] = make_int4(ei[e], et[e], __float_as_int(ew[e]), 0);
}

// rel16[r,b,:] = fp16( relu(relrep[b,r,:] @ w1 + b1) @ w2 + b2 )
__global__ void rel_mlp(const float* __restrict__ relrep,
                        const float* __restrict__ w1, const float* __restrict__ b1,
                        const float* __restrict__ w2, const float* __restrict__ b2,
                        __half* __restrict__ rel16) {
    __shared__ float sin[ND];
    __shared__ float shid[ND];
    int br = blockIdx.x;                 // b*NR + r
    int b = br >> 6, r = br & 63;
    int j = threadIdx.x;
    sin[j] = relrep[br * ND + j];
    __syncthreads();
    float acc = b1[j];
    #pragma unroll 8
    for (int k = 0; k < ND; ++k) acc += sin[k] * w1[k * ND + j];
    shid[j] = fmaxf(acc, 0.f);
    __syncthreads();
    float out = b2[j];
    #pragma unroll 8
    for (int k = 0; k < ND; ++k) out += shid[k] * w2[k * ND + j];
    rel16[(r * NB + b) * ND + j] = __float2half(out);
}

__device__ __forceinline__ float2 h2f(unsigned u) {
    __half2 h = *(__half2*)&u;
    return __half22float2(h);
}

// ------------------------------------------------ fused gather+MFMA-conv+LN
// block = 4 waves = 4 nodes. Wave wv gathers node (blk*4+wv) for all batches
// (lane: b=lane>>4, channels 4*(lane&15)+0..3), stages A16[16 rows][128 K]
// fp16 in LDS (row = nl*4+b, K = [x | agg]), then each wave computes a 16x16
// output tile via 4x mfma_f32_16x16x32_f16, then LN+residual on its node.
__global__ void __launch_bounds__(256)
fused_layer(const float* __restrict__ x, const __half* __restrict__ x16,
            const __half* __restrict__ rel16,
            const int* __restrict__ row_off, const int4* __restrict__ epack,
            const float* __restrict__ query, const int* __restrict__ h_index,
            const _Float16* __restrict__ cwt, const float* __restrict__ cb,
            const float* __restrict__ g, const float* __restrict__ bb,
            float* __restrict__ xo, __half* __restrict__ xo16) {
    __shared__ _Float16 A16[16 * 136];     // stride 136 halves (272 B): 2-way only
    __shared__ float sD[16 * 65];
    int wv = threadIdx.x >> 6;
    int lane = threadIdx.x & 63;
    int n = blockIdx.x * 4 + wv;
    int beg = row_off[n], end = row_off[n + 1];

    const uint2* __restrict__ x2 = (const uint2*)x16;    // 4 halves / lane
    const uint2* __restrict__ r2 = (const uint2*)rel16;

    float4 agg4 = make_float4(0.f, 0.f, 0.f, 0.f);
    for (int e0 = beg; e0 < end; e0 += 64) {
        int cnt = min(64, end - e0);
        int4 ed = make_int4(0, 0, 0, 0);
        if (lane < cnt) ed = epack[e0 + lane];
        int j = 0;
        for (; j + 4 <= cnt; j += 4) {
            int s0 = __shfl(ed.x, j    ), t0 = __shfl(ed.y, j    );
            int s1 = __shfl(ed.x, j + 1), t1 = __shfl(ed.y, j + 1);
            int s2 = __shfl(ed.x, j + 2), t2 = __shfl(ed.y, j + 2);
            int s3 = __shfl(ed.x, j + 3), t3 = __shfl(ed.y, j + 3);
            float w0 = __int_as_float(__shfl(ed.z, j    ));
            float w1 = __int_as_float(__shfl(ed.z, j + 1));
            float w2 = __int_as_float(__shfl(ed.z, j + 2));
            float w3 = __int_as_float(__shfl(ed.z, j + 3));
            uint2 xa = x2[s0 * 64 + lane], ra = r2[t0 * 64 + lane];
            uint2 xb = x2[s1 * 64 + lane], rb = r2[t1 * 64 + lane];
            uint2 xc = x2[s2 * 64 + lane], rc = r2[t2 * 64 + lane];
            uint2 xd = x2[s3 * 64 + lane], rd = r2[t3 * 64 + lane];
            float2 p0, p1, q0, q1;
            p0 = h2f(xa.x); p1 = h2f(xa.y); q0 = h2f(ra.x); q1 = h2f(ra.y);
            agg4.x = fmaf(p0.x * q0.x, w0, agg4.x);
            agg4.y = fmaf(p0.y * q0.y, w0, agg4.y);
            agg4.z = fmaf(p1.x * q1.x, w0, agg4.z);
            agg4.w = fmaf(p1.y * q1.y, w0, agg4.w);
            p0 = h2f(xb.x); p1 = h2f(xb.y); q0 = h2f(rb.x); q1 = h2f(rb.y);
            agg4.x = fmaf(p0.x * q0.x, w1, agg4.x);
            agg4.y = fmaf(p0.y * q0.y, w1, agg4.y);
            agg4.z = fmaf(p1.x * q1.x, w1, agg4.z);
            agg4.w = fmaf(p1.y * q1.y, w1, agg4.w);
            p0 = h2f(xc.x); p1 = h2f(xc.y); q0 = h2f(rc.x); q1 = h2f(rc.y);
            agg4.x = fmaf(p0.x * q0.x, w2, agg4.x);
            agg4.y = fmaf(p0.y * q0.y, w2, agg4.y);
            agg4.z = fmaf(p1.x * q1.x, w2, agg4.z);
            agg4.w = fmaf(p1.y * q1.y, w2, agg4.w);
            p0 = h2f(xd.x); p1 = h2f(xd.y); q0 = h2f(rd.x); q1 = h2f(rd.y);
            agg4.x = fmaf(p0.x * q0.x, w3, agg4.x);
            agg4.y = fmaf(p0.y * q0.y, w3, agg4.y);
            agg4.z = fmaf(p1.x * q1.x, w3, agg4.z);
            agg4.w = fmaf(p1.y * q1.y, w3, agg4.w);
        }
        for (; j < cnt; ++j) {
            int s   = __shfl(ed.x, j);
            int t   = __shfl(ed.y, j);
            float w = __int_as_float(__shfl(ed.z, j));
            uint2 xa = x2[s * 64 + lane], ra = r2[t * 64 + lane];
            float2 p0 = h2f(xa.x), p1 = h2f(xa.y), q0 = h2f(ra.x), q1 = h2f(ra.y);
            agg4.x = fmaf(p0.x * q0.x, w, agg4.x);
            agg4.y = fmaf(p0.y * q0.y, w, agg4.y);
            agg4.z = fmaf(p1.x * q1.x, w, agg4.z);
            agg4.w = fmaf(p1.y * q1.y, w, agg4.w);
        }
    }
    int bidx = lane >> 4, c4 = (lane & 15) << 2;
    // boundary self-loop
    if (n == h_index[bidx]) {
        const float4* qf4 = (const float4*)query;
        float4 q4 = qf4[lane];
        agg4.x += q4.x; agg4.y += q4.y; agg4.z += q4.z; agg4.w += q4.w;
    }
    // stage A16 row r = wv*4 + b : cols [0,64) = x16, [64,128) = fp16(agg)
    {
        int r = wv * 4 + bidx;
        uint2 xraw = x2[(n * NB + bidx) * 16 + (lane & 15)];
        *(uint2*)&A16[r * 136 + c4] = xraw;                 // bit-copy 4 halves
        half4v ah;
        ah.x = (_Float16)agg4.x; ah.y = (_Float16)agg4.y;
        ah.z = (_Float16)agg4.z; ah.w = (_Float16)agg4.w;
        *(half4v*)&A16[r * 136 + 64 + c4] = ah;
    }
    __syncthreads();
    // MFMA: wave wv computes output cols [wv*16, wv*16+16)
    {
        int m = lane & 15, quad = lane >> 4;
        int ncol = wv * 16 + m;
        floatx4 acc = {0.f, 0.f, 0.f, 0.f};
        #pragma unroll
        for (int k0 = 0; k0 < 128; k0 += 32) {
            half8 a = *(const half8*)&A16[m * 136 + k0 + quad * 8];
            half8 bfr = *(const half8*)&cwt[ncol * 128 + k0 + quad * 8];
            acc = __builtin_amdgcn_mfma_f32_16x16x32_f16(a, bfr, acc, 0, 0, 0);
        }
        #pragma unroll
        for (int rg = 0; rg < 4; ++rg)
            sD[(quad * 4 + rg) * 65 + ncol] = acc[rg];
    }
    __syncthreads();
    // LN + relu + residual on this wave's node (rows wv*4 + b)
    float gl = g[lane], bl = bb[lane], cbl = cb[lane];
    #pragma unroll
    for (int b = 0; b < NB; ++b) {
        float acc = sD[(wv * 4 + b) * 65 + lane] + cbl;
        float s = acc, s2 = acc * acc;
        #pragma unroll
        for (int o = 32; o > 0; o >>= 1) { s += __shfl_xor(s, o); s2 += __shfl_xor(s2, o); }
        float mu  = s * (1.f / ND);
        float var = s2 * (1.f / ND) - mu * mu;
        float hn  = (acc - mu) * rsqrtf(var + LN_EPS) * gl + bl;
        float xvf = x[(n * NB + b) * ND + lane];
        float v   = fmaxf(hn, 0.f) + xvf;
        xo[(n * NB + b) * ND + lane] = v;
        xo16[(n * NB + b) * ND + lane] = __float2half(v);
    }
}

// score[b,t] = relu(concat(x[ti,b,:],query[b,:]) @ W1 + b1) @ W2 + b2
__global__ void final_score(const float* __restrict__ x, const float* __restrict__ query,
                            const int* __restrict__ t_index,
                            const float* __restrict__ w1, const float* __restrict__ b1,
                            const float* __restrict__ w2, const float* __restrict__ b2,
                            float* __restrict__ out) {
    int gid = blockIdx.x * 4 + (threadIdx.x >> 6);
    int lane = threadIdx.x & 63;
    int b = gid / NT;
    int ti = t_index[gid];
    float xv = x[(ti * NB + b) * ND + lane];
    float qv = query[b * ND + lane];
    float a0 = b1[lane], a1 = b1[lane + 64];
    #pragma unroll 8
    for (int k = 0; k < ND; ++k) {
        float f = __shfl(xv, k);
        a0 += f * w1[k * 128 + lane];
        a1 += f * w1[k * 128 + lane + 64];
    }
    #pragma unroll 8
    for (int k = 0; k < ND; ++k) {
        float f = __shfl(qv, k);
        a0 += f * w1[(ND + k) * 128 + lane];
        a1 += f * w1[(ND + k) * 128 + lane + 64];
    }
    a0 = fmaxf(a0, 0.f);
    a1 = fmaxf(a1, 0.f);
    float p = a0 * w2[lane] + a1 * w2[lane + 64];
    #pragma unroll
    for (int o = 32; o > 0; o >>= 1) p += __shfl_xor(p, o);
    if (lane == 0) out[gid] = p + b2[0];
}

extern "C" void kernel_launch(void* const* d_in, const int* in_sizes, int n_in,
                              void* d_out, int out_size, void* d_ws, size_t ws_size,
                              hipStream_t stream) {
    const int*   edge_index  = (const int*)d_in[0];
    const int*   edge_type   = (const int*)d_in[1];
    const float* relrep      = (const float*)d_in[2];
    const int*   h_index     = (const int*)d_in[3];
    const int*   r_index     = (const int*)d_in[4];
    const int*   t_index     = (const int*)d_in[5];
    const float* edge_weight = (const float*)d_in[6];
    const float* rp_w1  = (const float*)d_in[7];
    const float* rp_b1  = (const float*)d_in[8];
    const float* rp_w2  = (const float*)d_in[9];
    const float* rp_b2  = (const float*)d_in[10];
    const float* conv_w = (const float*)d_in[11];
    const float* conv_b = (const float*)d_in[12];
    const float* ln_g   = (const float*)d_in[13];
    const float* ln_b   = (const float*)d_in[14];
    const float* mlp_w1 = (const float*)d_in[15];
    const float* mlp_b1 = (const float*)d_in[16];
    const float* mlp_w2 = (const float*)d_in[17];
    const float* mlp_b2 = (const float*)d_in[18];
    float* out = (float*)d_out;

    const int BND = NB * NN * ND;              // 5,120,000
    float*    ws     = (float*)d_ws;
    float*    query  = ws;                       // 256
    __half*   rel16  = (__half*)(query + 256);   // 16384 halves
    float*    x0     = (float*)(rel16 + NB * NR * ND);  // BND fp32
    float*    x1     = x0 + BND;                 // BND fp32
    __half*   x16a   = (__half*)(x1 + BND);      // BND halves
    __half*   x16b   = x16a + BND;               // BND halves
    _Float16* cwt16  = (_Float16*)(x16b + BND);  // L*64*128 halves
    int4*     epack  = (int4*)(cwt16 + NL * 8192); // NE int4
    int*      deg    = (int*)(epack + NE);       // NN
    int*      row_off = deg + NN;                // NN+1
    int*      cursor  = row_off + NN + 1;        // NN

    // --- CSR build + weight prep (once per call, reused across layers) ---
    zero_i<<<(NN + 255) / 256, 256, 0, stream>>>(deg, NN);
    hist_dst<<<(NE + 255) / 256, 256, 0, stream>>>(edge_index, deg);
    scan_deg<<<1, 1024, 0, stream>>>(deg, row_off, cursor);
    scatter_edges<<<(NE + 255) / 256, 256, 0, stream>>>(edge_index, edge_type, edge_weight,
                                                        cursor, epack);
    conv_w_prep<<<(NL * 128 * 64 + 255) / 256, 256, 0, stream>>>(conv_w, cwt16);

    // --- boundary / x0 (fp32 + fp16 mirror) ---
    compute_query<<<1, 256, 0, stream>>>(relrep, r_index, query);
    zero_f4<<<BND / 4 / 256, 256, 0, stream>>>((float4*)x0, BND / 4);
    zero_f4<<<BND / 8 / 256, 256, 0, stream>>>((float4*)x16a, BND / 8);
    scatter_query<<<1, 256, 0, stream>>>(x0, x16a, query, h_index);

    float*  xc = x0;   float*  xn = x1;
    __half* mc = x16a; __half* mn = x16b;
    for (int l = 0; l < NL; ++l) {
        rel_mlp<<<NB * NR, 64, 0, stream>>>(relrep,
                                            rp_w1 + l * ND * ND, rp_b1 + l * ND,
                                            rp_w2 + l * ND * ND, rp_b2 + l * ND, rel16);
        fused_layer<<<NN / 4, 256, 0, stream>>>(xc, mc, rel16, row_off, epack,
                                                query, h_index,
                                                cwt16 + l * 8192, conv_b + l * ND,
                                                ln_g + l * ND, ln_b + l * ND, xn, mn);
        float* tf = xc; xc = xn; xn = tf;
        __half* th = mc; mc = mn; mn = th;
    }
    final_score<<<NB * NT / 4, 256, 0, stream>>>(xc, query, t_index,
                                                 mlp_w1, mlp_b1, mlp_w2, mlp_b2, out);
}

// Round 7
// 413.543 us; speedup vs baseline: 2.5752x; 1.1240x over previous
//
#include <hip/hip_runtime.h>
#include <hip/hip_fp16.h>

#define NB 4
#define NN 20000
#define NE 320000
#define ND 64
#define NR 64
#define NT 1000
#define NL 6
#define LN_EPS 1e-5f

typedef _Float16 half8 __attribute__((ext_vector_type(8)));
typedef _Float16 half4v __attribute__((ext_vector_type(4)));
typedef float floatx4 __attribute__((ext_vector_type(4)));

// State: fp16 ONLY, [N,B,D] node-major (one node = 512 B for all batches).
// All intra-layer math (message accum, conv accum, LN, residual) in fp32;
// only the stored state rounds to fp16. The residual source is read back
// from the A16 LDS tile (already holds x16[n] in epilogue layout), so the
// layer kernel touches no fp32 state at all: r6's 41 MB/layer of fp32
// read+write traffic is gone, and dur was tracking bytes/2.4TB/s.

// ---------------------------------------------------------------- utilities
__global__ void zero_f4(float4* __restrict__ p, int n4) {
    int i = blockIdx.x * blockDim.x + threadIdx.x;
    if (i < n4) p[i] = make_float4(0.f, 0.f, 0.f, 0.f);
}

__global__ void zero_i(int* __restrict__ p, int n) {
    int i = blockIdx.x * blockDim.x + threadIdx.x;
    if (i < n) p[i] = 0;
}

__global__ void compute_query(const float* __restrict__ relrep,
                              const int* __restrict__ r_index,
                              float* __restrict__ query) {
    int tid = threadIdx.x;
    int b = tid >> 6, d = tid & 63;
    query[tid] = relrep[(b * NR + r_index[b]) * ND + d];
}

__global__ void scatter_query(__half* __restrict__ buf16,
                              const float* __restrict__ query,
                              const int* __restrict__ h_index) {
    int tid = threadIdx.x;
    int b = tid >> 6, d = tid & 63;
    buf16[(h_index[b] * NB + b) * ND + d] = __float2half(query[tid]);
}

// conv_w [L][2D][D] fp32 -> transposed fp16 [L][D out][2D in]
__global__ void conv_w_prep(const float* __restrict__ cw, _Float16* __restrict__ cwt) {
    int i = blockIdx.x * 256 + threadIdx.x;          // over L*128*64
    if (i >= NL * 128 * 64) return;
    int l = i >> 13, rem = i & 8191, k = rem >> 6, n = rem & 63;
    cwt[l * 8192 + n * 128 + k] = (_Float16)cw[i];
}

// ---------------------------------------------------------------- CSR build
__global__ void hist_dst(const int* __restrict__ ei, int* __restrict__ deg) {
    int e = blockIdx.x * blockDim.x + threadIdx.x;
    if (e < NE) atomicAdd(&deg[ei[NE + e]], 1);
}

// 1024 threads, each scans 20 contiguous elements serially; single LDS scan.
__global__ void scan_deg(const int* __restrict__ deg, int* __restrict__ row_off,
                         int* __restrict__ cursor) {
    __shared__ int part[1024];
    int tid = threadIdx.x;
    int base = tid * 20;
    int loc[20];
    int sum = 0;
    #pragma unroll
    for (int k = 0; k < 20; ++k) {
        int i = base + k;
        int v = (i < NN) ? deg[i] : 0;
        loc[k] = sum;               // exclusive local prefix
        sum += v;
    }
    part[tid] = sum;
    __syncthreads();
    for (int o = 1; o < 1024; o <<= 1) {
        int t = (tid >= o) ? part[tid - o] : 0;
        __syncthreads();
        part[tid] += t;
        __syncthreads();
    }
    int offset = (tid > 0) ? part[tid - 1] : 0;
    #pragma unroll
    for (int k = 0; k < 20; ++k) {
        int i = base + k;
        if (i < NN) { int v = offset + loc[k]; row_off[i] = v; cursor[i] = v; }
    }
    if (tid == 1023) row_off[NN] = part[1023];
}

__global__ void scatter_edges(const int* __restrict__ ei, const int* __restrict__ et,
                              const float* __restrict__ ew, int* __restrict__ cursor,
                              int4* __restrict__ epack) {
    int e = blockIdx.x * blockDim.x + threadIdx.x;
    if (e >= NE) return;
    int d = ei[NE + e];
    int p = atomicAdd(&cursor[d], 1);
    epack[p] = make_int4(ei[e], et[e], __float_as_int(ew[e]), 0);
}

// rel16 for ALL layers in one launch: rel16[l][r,b,:] (grid = NL*256 waves)
__global__ void rel_mlp_all(const float* __restrict__ relrep,
                            const float* __restrict__ rp_w1, const float* __restrict__ rp_b1,
                            const float* __restrict__ rp_w2, const float* __restrict__ rp_b2,
                            __half* __restrict__ rel16) {
    __shared__ float sin[ND];
    __shared__ float shid[ND];
    int l = blockIdx.x >> 8;
    int br = blockIdx.x & 255;           // b*NR + r
    int b = br >> 6, r = br & 63;
    int j = threadIdx.x;
    const float* w1 = rp_w1 + l * ND * ND;
    const float* b1 = rp_b1 + l * ND;
    const float* w2 = rp_w2 + l * ND * ND;
    const float* b2 = rp_b2 + l * ND;
    sin[j] = relrep[br * ND + j];
    __syncthreads();
    float acc = b1[j];
    #pragma unroll 8
    for (int k = 0; k < ND; ++k) acc += sin[k] * w1[k * ND + j];
    shid[j] = fmaxf(acc, 0.f);
    __syncthreads();
    float out = b2[j];
    #pragma unroll 8
    for (int k = 0; k < ND; ++k) out += shid[k] * w2[k * ND + j];
    rel16[l * (NR * NB * ND) + (r * NB + b) * ND + j] = __float2half(out);
}

__device__ __forceinline__ float2 h2f(unsigned u) {
    __half2 h = *(__half2*)&u;
    return __half22float2(h);
}

// ------------------------------------------------ fused gather+MFMA-conv+LN
// block = 4 waves = 4 nodes. Wave wv gathers node (blk*4+wv) for all batches
// (lane: b=lane>>4, channels 4*(lane&15)+0..3), stages A16[16 rows][128 K]
// fp16 in LDS (row = wv*4+b, K = [x | agg]); each wave computes a 16x16
// output tile via 4x mfma_f32_16x16x32_f16; epilogue LN+relu+residual with
// the residual read back from A16 (no fp32 state traffic).
__global__ void __launch_bounds__(256)
fused_layer(const __half* __restrict__ x16, const __half* __restrict__ rel16,
            const int* __restrict__ row_off, const int4* __restrict__ epack,
            const float* __restrict__ query, const int* __restrict__ h_index,
            const _Float16* __restrict__ cwt, const float* __restrict__ cb,
            const float* __restrict__ g, const float* __restrict__ bb,
            __half* __restrict__ xo16) {
    __shared__ _Float16 A16[16 * 136];     // stride 136 halves (272 B)
    __shared__ float sD[16 * 65];
    int wv = threadIdx.x >> 6;
    int lane = threadIdx.x & 63;
    int n = blockIdx.x * 4 + wv;
    int beg = row_off[n], end = row_off[n + 1];

    const uint2* __restrict__ x2 = (const uint2*)x16;    // 4 halves / lane
    const uint2* __restrict__ r2 = (const uint2*)rel16;

    float4 agg4 = make_float4(0.f, 0.f, 0.f, 0.f);
    for (int e0 = beg; e0 < end; e0 += 64) {
        int cnt = min(64, end - e0);
        int4 ed = make_int4(0, 0, 0, 0);
        if (lane < cnt) ed = epack[e0 + lane];
        int j = 0;
        for (; j + 4 <= cnt; j += 4) {
            int s0 = __shfl(ed.x, j    ), t0 = __shfl(ed.y, j    );
            int s1 = __shfl(ed.x, j + 1), t1 = __shfl(ed.y, j + 1);
            int s2 = __shfl(ed.x, j + 2), t2 = __shfl(ed.y, j + 2);
            int s3 = __shfl(ed.x, j + 3), t3 = __shfl(ed.y, j + 3);
            float w0 = __int_as_float(__shfl(ed.z, j    ));
            float w1 = __int_as_float(__shfl(ed.z, j + 1));
            float w2 = __int_as_float(__shfl(ed.z, j + 2));
            float w3 = __int_as_float(__shfl(ed.z, j + 3));
            uint2 xa = x2[s0 * 64 + lane], ra = r2[t0 * 64 + lane];
            uint2 xb = x2[s1 * 64 + lane], rb = r2[t1 * 64 + lane];
            uint2 xc = x2[s2 * 64 + lane], rc = r2[t2 * 64 + lane];
            uint2 xd = x2[s3 * 64 + lane], rd = r2[t3 * 64 + lane];
            float2 p0, p1, q0, q1;
            p0 = h2f(xa.x); p1 = h2f(xa.y); q0 = h2f(ra.x); q1 = h2f(ra.y);
            agg4.x = fmaf(p0.x * q0.x, w0, agg4.x);
            agg4.y = fmaf(p0.y * q0.y, w0, agg4.y);
            agg4.z = fmaf(p1.x * q1.x, w0, agg4.z);
            agg4.w = fmaf(p1.y * q1.y, w0, agg4.w);
            p0 = h2f(xb.x); p1 = h2f(xb.y); q0 = h2f(rb.x); q1 = h2f(rb.y);
            agg4.x = fmaf(p0.x * q0.x, w1, agg4.x);
            agg4.y = fmaf(p0.y * q0.y, w1, agg4.y);
            agg4.z = fmaf(p1.x * q1.x, w1, agg4.z);
            agg4.w = fmaf(p1.y * q1.y, w1, agg4.w);
            p0 = h2f(xc.x); p1 = h2f(xc.y); q0 = h2f(rc.x); q1 = h2f(rc.y);
            agg4.x = fmaf(p0.x * q0.x, w2, agg4.x);
            agg4.y = fmaf(p0.y * q0.y, w2, agg4.y);
            agg4.z = fmaf(p1.x * q1.x, w2, agg4.z);
            agg4.w = fmaf(p1.y * q1.y, w2, agg4.w);
            p0 = h2f(xd.x); p1 = h2f(xd.y); q0 = h2f(rd.x); q1 = h2f(rd.y);
            agg4.x = fmaf(p0.x * q0.x, w3, agg4.x);
            agg4.y = fmaf(p0.y * q0.y, w3, agg4.y);
            agg4.z = fmaf(p1.x * q1.x, w3, agg4.z);
            agg4.w = fmaf(p1.y * q1.y, w3, agg4.w);
        }
        for (; j < cnt; ++j) {
            int s   = __shfl(ed.x, j);
            int t   = __shfl(ed.y, j);
            float w = __int_as_float(__shfl(ed.z, j));
            uint2 xa = x2[s * 64 + lane], ra = r2[t * 64 + lane];
            float2 p0 = h2f(xa.x), p1 = h2f(xa.y), q0 = h2f(ra.x), q1 = h2f(ra.y);
            agg4.x = fmaf(p0.x * q0.x, w, agg4.x);
            agg4.y = fmaf(p0.y * q0.y, w, agg4.y);
            agg4.z = fmaf(p1.x * q1.x, w, agg4.z);
            agg4.w = fmaf(p1.y * q1.y, w, agg4.w);
        }
    }
    int bidx = lane >> 4, c4 = (lane & 15) << 2;
    // boundary self-loop
    if (n == h_index[bidx]) {
        const float4* qf4 = (const float4*)query;
        float4 q4 = qf4[lane];
        agg4.x += q4.x; agg4.y += q4.y; agg4.z += q4.z; agg4.w += q4.w;
    }
    // stage A16 row r = wv*4 + b : cols [0,64) = x16, [64,128) = fp16(agg)
    {
        int r = wv * 4 + bidx;
        uint2 xraw = x2[(n * NB + bidx) * 16 + (lane & 15)];
        *(uint2*)&A16[r * 136 + c4] = xraw;                 // bit-copy 4 halves
        half4v ah;
        ah.x = (_Float16)agg4.x; ah.y = (_Float16)agg4.y;
        ah.z = (_Float16)agg4.z; ah.w = (_Float16)agg4.w;
        *(half4v*)&A16[r * 136 + 64 + c4] = ah;
    }
    __syncthreads();
    // MFMA: wave wv computes output cols [wv*16, wv*16+16)
    {
        int m = lane & 15, quad = lane >> 4;
        int ncol = wv * 16 + m;
        floatx4 acc = {0.f, 0.f, 0.f, 0.f};
        #pragma unroll
        for (int k0 = 0; k0 < 128; k0 += 32) {
            half8 a = *(const half8*)&A16[m * 136 + k0 + quad * 8];
            half8 bfr = *(const half8*)&cwt[ncol * 128 + k0 + quad * 8];
            acc = __builtin_amdgcn_mfma_f32_16x16x32_f16(a, bfr, acc, 0, 0, 0);
        }
        #pragma unroll
        for (int rg = 0; rg < 4; ++rg)
            sD[(quad * 4 + rg) * 65 + ncol] = acc[rg];
    }
    __syncthreads();
    // LN + relu + residual; residual source = A16 x-columns (fp16 state)
    float gl = g[lane], bl = bb[lane], cbl = cb[lane];
    #pragma unroll
    for (int b = 0; b < NB; ++b) {
        float acc = sD[(wv * 4 + b) * 65 + lane] + cbl;
        float s = acc, s2 = acc * acc;
        #pragma unroll
        for (int o = 32; o > 0; o >>= 1) { s += __shfl_xor(s, o); s2 += __shfl_xor(s2, o); }
        float mu  = s * (1.f / ND);
        float var = s2 * (1.f / ND) - mu * mu;
        float hn  = (acc - mu) * rsqrtf(var + LN_EPS) * gl + bl;
        float xvf = (float)A16[(wv * 4 + b) * 136 + lane];
        float v   = fmaxf(hn, 0.f) + xvf;
        xo16[(n * NB + b) * ND + lane] = __float2half(v);
    }
}

// score[b,t] = relu(concat(x[ti,b,:],query[b,:]) @ W1 + b1) @ W2 + b2
__global__ void final_score(const __half* __restrict__ x16, const float* __restrict__ query,
                            const int* __restrict__ t_index,
                            const float* __restrict__ w1, const float* __restrict__ b1,
                            const float* __restrict__ w2, const float* __restrict__ b2,
                            float* __restrict__ out) {
    int gid = blockIdx.x * 4 + (threadIdx.x >> 6);
    int lane = threadIdx.x & 63;
    int b = gid / NT;
    int ti = t_index[gid];
    float xv = __half2float(x16[(ti * NB + b) * ND + lane]);
    float qv = query[b * ND + lane];
    float a0 = b1[lane], a1 = b1[lane + 64];
    #pragma unroll 8
    for (int k = 0; k < ND; ++k) {
        float f = __shfl(xv, k);
        a0 += f * w1[k * 128 + lane];
        a1 += f * w1[k * 128 + lane + 64];
    }
    #pragma unroll 8
    for (int k = 0; k < ND; ++k) {
        float f = __shfl(qv, k);
        a0 += f * w1[(ND + k) * 128 + lane];
        a1 += f * w1[(ND + k) * 128 + lane + 64];
    }
    a0 = fmaxf(a0, 0.f);
    a1 = fmaxf(a1, 0.f);
    float p = a0 * w2[lane] + a1 * w2[lane + 64];
    #pragma unroll
    for (int o = 32; o > 0; o >>= 1) p += __shfl_xor(p, o);
    if (lane == 0) out[gid] = p + b2[0];
}

extern "C" void kernel_launch(void* const* d_in, const int* in_sizes, int n_in,
                              void* d_out, int out_size, void* d_ws, size_t ws_size,
                              hipStream_t stream) {
    const int*   edge_index  = (const int*)d_in[0];
    const int*   edge_type   = (const int*)d_in[1];
    const float* relrep      = (const float*)d_in[2];
    const int*   h_index     = (const int*)d_in[3];
    const int*   r_index     = (const int*)d_in[4];
    const int*   t_index     = (const int*)d_in[5];
    const float* edge_weight = (const float*)d_in[6];
    const float* rp_w1  = (const float*)d_in[7];
    const float* rp_b1  = (const float*)d_in[8];
    const float* rp_w2  = (const float*)d_in[9];
    const float* rp_b2  = (const float*)d_in[10];
    const float* conv_w = (const float*)d_in[11];
    const float* conv_b = (const float*)d_in[12];
    const float* ln_g   = (const float*)d_in[13];
    const float* ln_b   = (const float*)d_in[14];
    const float* mlp_w1 = (const float*)d_in[15];
    const float* mlp_b1 = (const float*)d_in[16];
    const float* mlp_w2 = (const float*)d_in[17];
    const float* mlp_b2 = (const float*)d_in[18];
    float* out = (float*)d_out;

    const int BND = NB * NN * ND;              // 5,120,000
    const int RELSZ = NR * NB * ND;            // 16384
    float*    ws     = (float*)d_ws;
    float*    query  = ws;                         // 256 f
    __half*   rel16  = (__half*)(query + 256);     // NL*RELSZ halves
    __half*   x16a   = rel16 + NL * RELSZ;         // BND halves
    __half*   x16b   = x16a + BND;                 // BND halves
    _Float16* cwt16  = (_Float16*)(x16b + BND);    // NL*8192 halves
    int4*     epack  = (int4*)(cwt16 + NL * 8192); // NE int4
    int*      deg    = (int*)(epack + NE);         // NN
    int*      row_off = deg + NN;                  // NN+1
    int*      cursor  = row_off + NN + 1;          // NN
    // total ≈ 26.5 MB

    // --- CSR build + weight prep (once per call, reused across layers) ---
    zero_i<<<(NN + 255) / 256, 256, 0, stream>>>(deg, NN);
    hist_dst<<<(NE + 255) / 256, 256, 0, stream>>>(edge_index, deg);
    scan_deg<<<1, 1024, 0, stream>>>(deg, row_off, cursor);
    scatter_edges<<<(NE + 255) / 256, 256, 0, stream>>>(edge_index, edge_type, edge_weight,
                                                        cursor, epack);
    conv_w_prep<<<(NL * 128 * 64 + 255) / 256, 256, 0, stream>>>(conv_w, cwt16);

    // --- boundary / x0 (fp16 state) + all-layer rel MLP ---
    compute_query<<<1, 256, 0, stream>>>(relrep, r_index, query);
    zero_f4<<<BND / 8 / 256, 256, 0, stream>>>((float4*)x16a, BND / 8);
    scatter_query<<<1, 256, 0, stream>>>(x16a, query, h_index);
    rel_mlp_all<<<NL * 256, 64, 0, stream>>>(relrep, rp_w1, rp_b1, rp_w2, rp_b2, rel16);

    __half* mc = x16a; __half* mn = x16b;
    for (int l = 0; l < NL; ++l) {
        fused_layer<<<NN / 4, 256, 0, stream>>>(mc, rel16 + l * RELSZ, row_off, epack,
                                                query, h_index,
                                                cwt16 + l * 8192, conv_b + l * ND,
                                                ln_g + l * ND, ln_b + l * ND, mn);
        __half* th = mc; mc = mn; mn = th;
    }
    final_score<<<NB * NT / 4, 256, 0, stream>>>(mc, query, t_index,
                                                 mlp_w1, mlp_b1, mlp_w2, mlp_b2, out);
}

// Round 8
// 387.641 us; speedup vs baseline: 2.7473x; 1.0668x over previous
//
#include <hip/hip_runtime.h>
#include <hip/hip_fp16.h>

#define NB 4
#define NN 20000
#define NE 320000
#define ND 64
#define NR 64
#define NT 1000
#define NL 6
#define LN_EPS 1e-5f

typedef _Float16 half8 __attribute__((ext_vector_type(8)));
typedef _Float16 half4v __attribute__((ext_vector_type(4)));
typedef float floatx4 __attribute__((ext_vector_type(4)));

// State: fp16 ONLY, [N,B,D] node-major. Layer 1 is specialized: x0 is zero
// except the 4 h-nodes, so its gather needs no x state (epack + L1-resident
// rel only) — bitwise identical to the generic path since skipped terms are
// exact zeros. Launch graph compacted to 10 dispatches.

// ---------------------------------------------------------------- utilities
__global__ void zero_i(int* __restrict__ p, int n) {
    int i = blockIdx.x * blockDim.x + threadIdx.x;
    if (i < n) p[i] = 0;
}

// ---------------------------------------------------------------- prep A
// blocks [0,1250): hist_dst ; [1250,1442): conv_w_prep ; 1442: compute_query
__global__ void __launch_bounds__(256)
prep_a(const int* __restrict__ ei, int* __restrict__ deg,
       const float* __restrict__ cw, _Float16* __restrict__ cwt,
       const float* __restrict__ relrep, const int* __restrict__ r_index,
       float* __restrict__ query) {
    int blk = blockIdx.x, tid = threadIdx.x;
    if (blk < 1250) {
        int e = blk * 256 + tid;                    // NE = 1250*256 exactly
        atomicAdd(&deg[ei[NE + e]], 1);
    } else if (blk < 1442) {
        int i = (blk - 1250) * 256 + tid;           // NL*128*64 = 192*256
        int l = i >> 13, rem = i & 8191, k = rem >> 6, n = rem & 63;
        cwt[l * 8192 + n * 128 + k] = (_Float16)cw[i];
    } else {
        int b = tid >> 6, d = tid & 63;
        query[tid] = relrep[(b * NR + r_index[b]) * ND + d];
    }
}

// 1024 threads, each scans 20 contiguous elements serially; single LDS scan.
__global__ void scan_deg(const int* __restrict__ deg, int* __restrict__ row_off,
                         int* __restrict__ cursor) {
    __shared__ int part[1024];
    int tid = threadIdx.x;
    int base = tid * 20;
    int loc[20];
    int sum = 0;
    #pragma unroll
    for (int k = 0; k < 20; ++k) {
        int i = base + k;
        int v = (i < NN) ? deg[i] : 0;
        loc[k] = sum;
        sum += v;
    }
    part[tid] = sum;
    __syncthreads();
    for (int o = 1; o < 1024; o <<= 1) {
        int t = (tid >= o) ? part[tid - o] : 0;
        __syncthreads();
        part[tid] += t;
        __syncthreads();
    }
    int offset = (tid > 0) ? part[tid - 1] : 0;
    #pragma unroll
    for (int k = 0; k < 20; ++k) {
        int i = base + k;
        if (i < NN) { int v = offset + loc[k]; row_off[i] = v; cursor[i] = v; }
    }
    if (tid == 1023) row_off[NN] = part[1023];
}

// ---------------------------------------------------------------- prep B
// blocks [0,1250): scatter_edges ; [1250,1634): rel_mlp (wave-local, one
// (l,r) per block, wave = batch; shuffle broadcasts, no LDS/barriers)
__global__ void __launch_bounds__(256)
prep_b(const int* __restrict__ ei, const int* __restrict__ et,
       const float* __restrict__ ew, int* __restrict__ cursor,
       int4* __restrict__ epack,
       const float* __restrict__ relrep,
       const float* __restrict__ rp_w1, const float* __restrict__ rp_b1,
       const float* __restrict__ rp_w2, const float* __restrict__ rp_b2,
       __half* __restrict__ rel16) {
    int blk = blockIdx.x, tid = threadIdx.x;
    if (blk < 1250) {
        int e = blk * 256 + tid;
        int d = ei[NE + e];
        int p = atomicAdd(&cursor[d], 1);
        epack[p] = make_int4(ei[e], et[e], __float_as_int(ew[e]), 0);
    } else {
        int u = blk - 1250;                 // 0..383 = l*NR + r
        int l = u >> 6, r = u & 63;
        int b = tid >> 6, j = tid & 63;
        const float* w1 = rp_w1 + l * ND * ND;
        const float* w2 = rp_w2 + l * ND * ND;
        float xin = relrep[(b * NR + r) * ND + j];
        float acc = rp_b1[l * ND + j];
        #pragma unroll 8
        for (int k = 0; k < ND; ++k) acc += __shfl(xin, k) * w1[k * ND + j];
        float hmid = fmaxf(acc, 0.f);
        float outv = rp_b2[l * ND + j];
        #pragma unroll 8
        for (int k = 0; k < ND; ++k) outv += __shfl(hmid, k) * w2[k * ND + j];
        rel16[l * (NR * NB * ND) + (r * NB + b) * ND + j] = __float2half(outv);
    }
}

__device__ __forceinline__ float2 h2f(unsigned u) {
    __half2 h = *(__half2*)&u;
    return __half22float2(h);
}

// --------------------------------------------- shared epilogue (MFMA+LN)
// A16 row r=wv*4+b holds [x | agg] fp16; computes conv+LN+relu+residual and
// writes xo16. Must be called by all 256 threads.
__device__ __forceinline__ void conv_ln_epilogue(
        _Float16* A16, float* sD, int wv, int lane, int n,
        const _Float16* __restrict__ cwt, const float* __restrict__ cb,
        const float* __restrict__ g, const float* __restrict__ bb,
        __half* __restrict__ xo16) {
    __syncthreads();
    {
        int m = lane & 15, quad = lane >> 4;
        int ncol = wv * 16 + m;
        floatx4 acc = {0.f, 0.f, 0.f, 0.f};
        #pragma unroll
        for (int k0 = 0; k0 < 128; k0 += 32) {
            half8 a = *(const half8*)&A16[m * 136 + k0 + quad * 8];
            half8 bfr = *(const half8*)&cwt[ncol * 128 + k0 + quad * 8];
            acc = __builtin_amdgcn_mfma_f32_16x16x32_f16(a, bfr, acc, 0, 0, 0);
        }
        #pragma unroll
        for (int rg = 0; rg < 4; ++rg)
            sD[(quad * 4 + rg) * 65 + ncol] = acc[rg];
    }
    __syncthreads();
    float gl = g[lane], bl = bb[lane], cbl = cb[lane];
    #pragma unroll
    for (int b = 0; b < NB; ++b) {
        float acc = sD[(wv * 4 + b) * 65 + lane] + cbl;
        float s = acc, s2 = acc * acc;
        #pragma unroll
        for (int o = 32; o > 0; o >>= 1) { s += __shfl_xor(s, o); s2 += __shfl_xor(s2, o); }
        float mu  = s * (1.f / ND);
        float var = s2 * (1.f / ND) - mu * mu;
        float hn  = (acc - mu) * rsqrtf(var + LN_EPS) * gl + bl;
        float xvf = (float)A16[(wv * 4 + b) * 136 + lane];
        float v   = fmaxf(hn, 0.f) + xvf;
        xo16[(n * NB + b) * ND + lane] = __float2half(v);
    }
}

// ------------------------------------------------ layer 1 (x0 query-sparse)
// x0[src,b] = fp16(q_b) iff src == h_index[b], else 0 -> gather touches only
// epack + rel (L1/L2-resident). Bitwise identical to the generic path.
__global__ void __launch_bounds__(256)
fused_layer_first(const __half* __restrict__ rel16,
                  const int* __restrict__ row_off, const int4* __restrict__ epack,
                  const float* __restrict__ query, const int* __restrict__ h_index,
                  const _Float16* __restrict__ cwt, const float* __restrict__ cb,
                  const float* __restrict__ g, const float* __restrict__ bb,
                  __half* __restrict__ xo16) {
    __shared__ _Float16 A16[16 * 136];
    __shared__ float sD[16 * 65];
    int wv = threadIdx.x >> 6;
    int lane = threadIdx.x & 63;
    int n = blockIdx.x * 4 + wv;
    int beg = row_off[n], end = row_off[n + 1];
    int bidx = lane >> 4, c4 = (lane & 15) << 2;
    int hb = h_index[bidx];

    const uint2* __restrict__ r2 = (const uint2*)rel16;
    float4 q4 = ((const float4*)query)[lane];
    half4v qh;
    qh.x = (_Float16)q4.x; qh.y = (_Float16)q4.y;
    qh.z = (_Float16)q4.z; qh.w = (_Float16)q4.w;
    // fp16-rounded q as floats (matches generic path reading x16 = fp16(q))
    float qx = (float)qh.x, qy = (float)qh.y, qz = (float)qh.z, qw = (float)qh.w;

    float4 agg4 = make_float4(0.f, 0.f, 0.f, 0.f);
    for (int e0 = beg; e0 < end; e0 += 64) {
        int cnt = min(64, end - e0);
        int4 ed = make_int4(0, 0, 0, 0);
        if (lane < cnt) ed = epack[e0 + lane];
        for (int j = 0; j < cnt; ++j) {
            int s   = __shfl(ed.x, j);
            int t   = __shfl(ed.y, j);
            float w = __int_as_float(__shfl(ed.z, j));
            if (s == hb) {
                uint2 ra = r2[t * 64 + lane];
                float2 q0 = h2f(ra.x), q1 = h2f(ra.y);
                agg4.x = fmaf(qx * q0.x, w, agg4.x);
                agg4.y = fmaf(qy * q0.y, w, agg4.y);
                agg4.z = fmaf(qz * q1.x, w, agg4.z);
                agg4.w = fmaf(qw * q1.y, w, agg4.w);
            }
        }
    }
    // boundary self-loop (full-precision q, as in generic path)
    if (n == hb) {
        agg4.x += q4.x; agg4.y += q4.y; agg4.z += q4.z; agg4.w += q4.w;
    }
    // stage A16: x cols = fp16(q) iff n==hb else 0 ; agg cols = fp16(agg)
    {
        int r = wv * 4 + bidx;
        half4v xh = {0, 0, 0, 0};
        if (n == hb) xh = qh;
        *(half4v*)&A16[r * 136 + c4] = xh;
        half4v ah;
        ah.x = (_Float16)agg4.x; ah.y = (_Float16)agg4.y;
        ah.z = (_Float16)agg4.z; ah.w = (_Float16)agg4.w;
        *(half4v*)&A16[r * 136 + 64 + c4] = ah;
    }
    conv_ln_epilogue(A16, sD, wv, lane, n, cwt, cb, g, bb, xo16);
}

// ------------------------------------------------ generic fused layer
__global__ void __launch_bounds__(256)
fused_layer(const __half* __restrict__ x16, const __half* __restrict__ rel16,
            const int* __restrict__ row_off, const int4* __restrict__ epack,
            const float* __restrict__ query, const int* __restrict__ h_index,
            const _Float16* __restrict__ cwt, const float* __restrict__ cb,
            const float* __restrict__ g, const float* __restrict__ bb,
            __half* __restrict__ xo16) {
    __shared__ _Float16 A16[16 * 136];
    __shared__ float sD[16 * 65];
    int wv = threadIdx.x >> 6;
    int lane = threadIdx.x & 63;
    int n = blockIdx.x * 4 + wv;
    int beg = row_off[n], end = row_off[n + 1];

    const uint2* __restrict__ x2 = (const uint2*)x16;
    const uint2* __restrict__ r2 = (const uint2*)rel16;

    float4 agg4 = make_float4(0.f, 0.f, 0.f, 0.f);
    for (int e0 = beg; e0 < end; e0 += 64) {
        int cnt = min(64, end - e0);
        int4 ed = make_int4(0, 0, 0, 0);
        if (lane < cnt) ed = epack[e0 + lane];
        int j = 0;
        for (; j + 4 <= cnt; j += 4) {
            int s0 = __shfl(ed.x, j    ), t0 = __shfl(ed.y, j    );
            int s1 = __shfl(ed.x, j + 1), t1 = __shfl(ed.y, j + 1);
            int s2 = __shfl(ed.x, j + 2), t2 = __shfl(ed.y, j + 2);
            int s3 = __shfl(ed.x, j + 3), t3 = __shfl(ed.y, j + 3);
            float w0 = __int_as_float(__shfl(ed.z, j    ));
            float w1 = __int_as_float(__shfl(ed.z, j + 1));
            float w2 = __int_as_float(__shfl(ed.z, j + 2));
            float w3 = __int_as_float(__shfl(ed.z, j + 3));
            uint2 xa = x2[s0 * 64 + lane], ra = r2[t0 * 64 + lane];
            uint2 xb = x2[s1 * 64 + lane], rb = r2[t1 * 64 + lane];
            uint2 xc = x2[s2 * 64 + lane], rc = r2[t2 * 64 + lane];
            uint2 xd = x2[s3 * 64 + lane], rd = r2[t3 * 64 + lane];
            float2 p0, p1, q0, q1;
            p0 = h2f(xa.x); p1 = h2f(xa.y); q0 = h2f(ra.x); q1 = h2f(ra.y);
            agg4.x = fmaf(p0.x * q0.x, w0, agg4.x);
            agg4.y = fmaf(p0.y * q0.y, w0, agg4.y);
            agg4.z = fmaf(p1.x * q1.x, w0, agg4.z);
            agg4.w = fmaf(p1.y * q1.y, w0, agg4.w);
            p0 = h2f(xb.x); p1 = h2f(xb.y); q0 = h2f(rb.x); q1 = h2f(rb.y);
            agg4.x = fmaf(p0.x * q0.x, w1, agg4.x);
            agg4.y = fmaf(p0.y * q0.y, w1, agg4.y);
            agg4.z = fmaf(p1.x * q1.x, w1, agg4.z);
            agg4.w = fmaf(p1.y * q1.y, w1, agg4.w);
            p0 = h2f(xc.x); p1 = h2f(xc.y); q0 = h2f(rc.x); q1 = h2f(rc.y);
            agg4.x = fmaf(p0.x * q0.x, w2, agg4.x);
            agg4.y = fmaf(p0.y * q0.y, w2, agg4.y);
            agg4.z = fmaf(p1.x * q1.x, w2, agg4.z);
            agg4.w = fmaf(p1.y * q1.y, w2, agg4.w);
            p0 = h2f(xd.x); p1 = h2f(xd.y); q0 = h2f(rd.x); q1 = h2f(rd.y);
            agg4.x = fmaf(p0.x * q0.x, w3, agg4.x);
            agg4.y = fmaf(p0.y * q0.y, w3, agg4.y);
            agg4.z = fmaf(p1.x * q1.x, w3, agg4.z);
            agg4.w = fmaf(p1.y * q1.y, w3, agg4.w);
        }
        for (; j < cnt; ++j) {
            int s   = __shfl(ed.x, j);
            int t   = __shfl(ed.y, j);
            float w = __int_as_float(__shfl(ed.z, j));
            uint2 xa = x2[s * 64 + lane], ra = r2[t * 64 + lane];
            float2 p0 = h2f(xa.x), p1 = h2f(xa.y), q0 = h2f(ra.x), q1 = h2f(ra.y);
            agg4.x = fmaf(p0.x * q0.x, w, agg4.x);
            agg4.y = fmaf(p0.y * q0.y, w, agg4.y);
            agg4.z = fmaf(p1.x * q1.x, w, agg4.z);
            agg4.w = fmaf(p1.y * q1.y, w, agg4.w);
        }
    }
    int bidx = lane >> 4, c4 = (lane & 15) << 2;
    if (n == h_index[bidx]) {
        const float4* qf4 = (const float4*)query;
        float4 q4 = qf4[lane];
        agg4.x += q4.x; agg4.y += q4.y; agg4.z += q4.z; agg4.w += q4.w;
    }
    {
        int r = wv * 4 + bidx;
        uint2 xraw = x2[(n * NB + bidx) * 16 + (lane & 15)];
        *(uint2*)&A16[r * 136 + c4] = xraw;
        half4v ah;
        ah.x = (_Float16)agg4.x; ah.y = (_Float16)agg4.y;
        ah.z = (_Float16)agg4.z; ah.w = (_Float16)agg4.w;
        *(half4v*)&A16[r * 136 + 64 + c4] = ah;
    }
    conv_ln_epilogue(A16, sD, wv, lane, n, cwt, cb, g, bb, xo16);
}

// score[b,t] = relu(concat(x[ti,b,:],query[b,:]) @ W1 + b1) @ W2 + b2
__global__ void final_score(const __half* __restrict__ x16, const float* __restrict__ query,
                            const int* __restrict__ t_index,
                            const float* __restrict__ w1, const float* __restrict__ b1,
                            const float* __restrict__ w2, const float* __restrict__ b2,
                            float* __restrict__ out) {
    int gid = blockIdx.x * 4 + (threadIdx.x >> 6);
    int lane = threadIdx.x & 63;
    int b = gid / NT;
    int ti = t_index[gid];
    float xv = __half2float(x16[(ti * NB + b) * ND + lane]);
    float qv = query[b * ND + lane];
    float a0 = b1[lane], a1 = b1[lane + 64];
    #pragma unroll 8
    for (int k = 0; k < ND; ++k) {
        float f = __shfl(xv, k);
        a0 += f * w1[k * 128 + lane];
        a1 += f * w1[k * 128 + lane + 64];
    }
    #pragma unroll 8
    for (int k = 0; k < ND; ++k) {
        float f = __shfl(qv, k);
        a0 += f * w1[(ND + k) * 128 + lane];
        a1 += f * w1[(ND + k) * 128 + lane + 64];
    }
    a0 = fmaxf(a0, 0.f);
    a1 = fmaxf(a1, 0.f);
    float p = a0 * w2[lane] + a1 * w2[lane + 64];
    #pragma unroll
    for (int o = 32; o > 0; o >>= 1) p += __shfl_xor(p, o);
    if (lane == 0) out[gid] = p + b2[0];
}

extern "C" void kernel_launch(void* const* d_in, const int* in_sizes, int n_in,
                              void* d_out, int out_size, void* d_ws, size_t ws_size,
                              hipStream_t stream) {
    const int*   edge_index  = (const int*)d_in[0];
    const int*   edge_type   = (const int*)d_in[1];
    const float* relrep      = (const float*)d_in[2];
    const int*   h_index     = (const int*)d_in[3];
    const int*   r_index     = (const int*)d_in[4];
    const int*   t_index     = (const int*)d_in[5];
    const float* edge_weight = (const float*)d_in[6];
    const float* rp_w1  = (const float*)d_in[7];
    const float* rp_b1  = (const float*)d_in[8];
    const float* rp_w2  = (const float*)d_in[9];
    const float* rp_b2  = (const float*)d_in[10];
    const float* conv_w = (const float*)d_in[11];
    const float* conv_b = (const float*)d_in[12];
    const float* ln_g   = (const float*)d_in[13];
    const float* ln_b   = (const float*)d_in[14];
    const float* mlp_w1 = (const float*)d_in[15];
    const float* mlp_b1 = (const float*)d_in[16];
    const float* mlp_w2 = (const float*)d_in[17];
    const float* mlp_b2 = (const float*)d_in[18];
    float* out = (float*)d_out;

    const int BND = NB * NN * ND;              // 5,120,000
    const int RELSZ = NR * NB * ND;            // 16384
    float*    ws     = (float*)d_ws;
    float*    query  = ws;                         // 256 f
    __half*   rel16  = (__half*)(query + 256);     // NL*RELSZ halves
    __half*   x16a   = rel16 + NL * RELSZ;         // BND halves
    __half*   x16b   = x16a + BND;                 // BND halves
    _Float16* cwt16  = (_Float16*)(x16b + BND);    // NL*8192 halves
    int4*     epack  = (int4*)(cwt16 + NL * 8192); // NE int4
    int*      deg    = (int*)(epack + NE);         // NN
    int*      row_off = deg + NN;                  // NN+1
    int*      cursor  = row_off + NN + 1;          // NN

    // 10-dispatch graph
    zero_i<<<(NN + 255) / 256, 256, 0, stream>>>(deg, NN);
    prep_a<<<1443, 256, 0, stream>>>(edge_index, deg, conv_w, cwt16,
                                     relrep, r_index, query);
    scan_deg<<<1, 1024, 0, stream>>>(deg, row_off, cursor);
    prep_b<<<1634, 256, 0, stream>>>(edge_index, edge_type, edge_weight, cursor,
                                     epack, relrep, rp_w1, rp_b1, rp_w2, rp_b2, rel16);

    __half* mc = x16a; __half* mn = x16b;
    fused_layer_first<<<NN / 4, 256, 0, stream>>>(rel16, row_off, epack,
                                                  query, h_index,
                                                  cwt16, conv_b, ln_g, ln_b, mc);
    for (int l = 1; l < NL; ++l) {
        fused_layer<<<NN / 4, 256, 0, stream>>>(mc, rel16 + l * RELSZ, row_off, epack,
                                                query, h_index,
                                                cwt16 + l * 8192, conv_b + l * ND,
                                                ln_g + l * ND, ln_b + l * ND, mn);
        __half* th = mc; mc = mn; mn = th;
    }
    final_score<<<NB * NT / 4, 256, 0, stream>>>(mc, query, t_index,
                                                 mlp_w1, mlp_b1, mlp_w2, mlp_b2, out);
}